// Round 1
// baseline (345.853 us; speedup 1.0000x reference)
//
#include <hip/hip_runtime.h>

#define N_NODES 50000
#define N_EDGES 800000
#define CAP 64

__device__ __forceinline__ float readlane_f(float v, int l) {
    return __int_as_float(__builtin_amdgcn_readlane(__float_as_int(v), l));
}

// out[N,128] = A[N,128] @ W[128,128], f32. Block = 512 thr = 8 waves, wave does 8 rows.
__global__ __launch_bounds__(512) void gemm128_kernel(
    const float* __restrict__ A, const float* __restrict__ W,
    float* __restrict__ out, int nrows)
{
    __shared__ float2 Wl[128 * 64];   // Wl[k*64+c] = {W[k][c], W[k][c+64]}  (64 KB)
    int tid = threadIdx.x;
    for (int idx = tid; idx < 128 * 64; idx += 512) {
        int k = idx >> 6, c = idx & 63;
        Wl[idx] = make_float2(W[k * 128 + c], W[k * 128 + 64 + c]);
    }
    __syncthreads();
    int lane = tid & 63;
    int wave = (blockIdx.x << 3) + (tid >> 6);
    int row0 = wave << 3;
    if (row0 >= nrows) return;

    float x0[8], x1[8];
    #pragma unroll
    for (int r = 0; r < 8; r++) {
        x0[r] = A[(row0 + r) * 128 + lane];
        x1[r] = A[(row0 + r) * 128 + 64 + lane];
    }
    float2 acc[8];
    #pragma unroll
    for (int r = 0; r < 8; r++) acc[r] = make_float2(0.f, 0.f);

    for (int k = 0; k < 64; k++) {
        float2 wk = Wl[(k << 6) + lane];
        #pragma unroll
        for (int r = 0; r < 8; r++) {
            float xv = readlane_f(x0[r], k);
            acc[r].x = fmaf(xv, wk.x, acc[r].x);
            acc[r].y = fmaf(xv, wk.y, acc[r].y);
        }
    }
    for (int k = 0; k < 64; k++) {
        float2 wk = Wl[((64 + k) << 6) + lane];
        #pragma unroll
        for (int r = 0; r < 8; r++) {
            float xv = readlane_f(x1[r], k);
            acc[r].x = fmaf(xv, wk.x, acc[r].x);
            acc[r].y = fmaf(xv, wk.y, acc[r].y);
        }
    }
    #pragma unroll
    for (int r = 0; r < 8; r++) {
        out[(row0 + r) * 128 + lane] = acc[r].x;
        out[(row0 + r) * 128 + 64 + lane] = acc[r].y;
    }
}

__global__ __launch_bounds__(256) void count_kernel(
    const int* __restrict__ dstv, int* __restrict__ deg)
{
    int e = blockIdx.x * 256 + threadIdx.x;
    if (e < N_EDGES) atomicAdd(&deg[dstv[e]], 1);
}

__global__ __launch_bounds__(256) void scatter_kernel(
    const int* __restrict__ srcv, const int* __restrict__ dstv,
    int* __restrict__ cursor, int* __restrict__ list)
{
    int e = blockIdx.x * 256 + threadIdx.x;
    if (e < N_EDGES) {
        int d = dstv[e];
        int slot = atomicAdd(&cursor[d], 1);
        if (slot < CAP) list[d * CAP + slot] = srcv[e];
    }
}

// a_src[n][h] = sum_c h1[n, h*16+c]*att_src[h*16+c]; same for a_dst. Wave per node.
__global__ __launch_bounds__(256) void att1_kernel(
    const float* __restrict__ h, const float* __restrict__ att_src,
    const float* __restrict__ att_dst, float* __restrict__ a_src, float* __restrict__ a_dst)
{
    int lane = threadIdx.x & 63;
    int n = blockIdx.x * 4 + (threadIdx.x >> 6);
    float h0 = h[n * 128 + lane], hv = h[n * 128 + 64 + lane];
    float ps0 = h0 * att_src[lane], ps1 = hv * att_src[64 + lane];
    float pd0 = h0 * att_dst[lane], pd1 = hv * att_dst[64 + lane];
    #pragma unroll
    for (int m = 1; m < 16; m <<= 1) {
        ps0 += __shfl_xor(ps0, m);
        ps1 += __shfl_xor(ps1, m);
        pd0 += __shfl_xor(pd0, m);
        pd1 += __shfl_xor(pd1, m);
    }
    if ((lane & 15) == 0) {
        int g = lane >> 4;
        a_src[n * 8 + g] = ps0;
        a_src[n * 8 + 4 + g] = ps1;
        a_dst[n * 8 + g] = pd0;
        a_dst[n * 8 + 4 + g] = pd1;
    }
}

// Edge softmax (8 heads) + aggregate + bias + ELU. Wave per node.
__global__ __launch_bounds__(256) void agg1_kernel(
    const float* __restrict__ h, const int* __restrict__ list, const int* __restrict__ deg,
    const float* __restrict__ a_src, const float* __restrict__ a_dst,
    const float* __restrict__ bias, float* __restrict__ out)
{
    __shared__ float w_lds[4][64][8];
    __shared__ int s_lds[4][64];
    int lane = threadIdx.x & 63;
    int wv = threadIdx.x >> 6;
    int n = blockIdx.x * 4 + wv;
    int d = min(deg[n], CAP);
    bool valid = lane < d;
    int s = valid ? list[n * CAP + lane] : 0;

    float al[8];
    #pragma unroll
    for (int hh = 0; hh < 8; hh++) {
        float a = a_src[s * 8 + hh] + a_dst[n * 8 + hh];
        a = a > 0.f ? a : 0.2f * a;          // leaky_relu 0.2
        al[hh] = valid ? a : -INFINITY;
    }
    float mh[8];
    #pragma unroll
    for (int hh = 0; hh < 8; hh++) mh[hh] = al[hh];
    #pragma unroll
    for (int m = 1; m < 64; m <<= 1) {
        #pragma unroll
        for (int hh = 0; hh < 8; hh++) mh[hh] = fmaxf(mh[hh], __shfl_xor(mh[hh], m));
    }
    float eh[8], sh[8];
    #pragma unroll
    for (int hh = 0; hh < 8; hh++) {
        eh[hh] = valid ? __expf(al[hh] - mh[hh]) : 0.f;
        sh[hh] = eh[hh];
    }
    #pragma unroll
    for (int m = 1; m < 64; m <<= 1) {
        #pragma unroll
        for (int hh = 0; hh < 8; hh++) sh[hh] += __shfl_xor(sh[hh], m);
    }
    #pragma unroll
    for (int hh = 0; hh < 8; hh++) w_lds[wv][lane][hh] = eh[hh] / (sh[hh] + 1e-16f);
    s_lds[wv][lane] = s;
    __syncthreads();

    float acc0 = 0.f, acc1 = 0.f;
    int g0 = lane >> 4, g1 = 4 + (lane >> 4);
    for (int e = 0; e < d; e++) {
        int ss = s_lds[wv][e];
        float w0 = w_lds[wv][e][g0];
        float w1 = w_lds[wv][e][g1];
        acc0 = fmaf(w0, h[ss * 128 + lane], acc0);
        acc1 = fmaf(w1, h[ss * 128 + 64 + lane], acc1);
    }
    float o0 = acc0 + bias[lane];
    float o1 = acc1 + bias[64 + lane];
    o0 = o0 > 0.f ? o0 : __expf(o0) - 1.f;   // ELU
    o1 = o1 > 0.f ? o1 : __expf(o1) - 1.f;
    out[n * 128 + lane] = o0;
    out[n * 128 + 64 + lane] = o1;
}

__global__ __launch_bounds__(256) void att2_kernel(
    const float* __restrict__ h, const float* __restrict__ att_src,
    const float* __restrict__ att_dst, float* __restrict__ a_src, float* __restrict__ a_dst)
{
    int lane = threadIdx.x & 63;
    int n = blockIdx.x * 4 + (threadIdx.x >> 6);
    float h0 = h[n * 128 + lane], hv = h[n * 128 + 64 + lane];
    float ps = h0 * att_src[lane] + hv * att_src[64 + lane];
    float pd = h0 * att_dst[lane] + hv * att_dst[64 + lane];
    #pragma unroll
    for (int m = 1; m < 64; m <<= 1) { ps += __shfl_xor(ps, m); pd += __shfl_xor(pd, m); }
    if (lane == 0) { a_src[n] = ps; a_dst[n] = pd; }
}

// Edge softmax (1 head) + aggregate + bias -> final output. Wave per node.
__global__ __launch_bounds__(256) void agg2_kernel(
    const float* __restrict__ h, const int* __restrict__ list, const int* __restrict__ deg,
    const float* __restrict__ a_src, const float* __restrict__ a_dst,
    const float* __restrict__ bias, float* __restrict__ out)
{
    __shared__ float w_lds[4][64];
    __shared__ int s_lds[4][64];
    int lane = threadIdx.x & 63;
    int wv = threadIdx.x >> 6;
    int n = blockIdx.x * 4 + wv;
    int d = min(deg[n], CAP);
    bool valid = lane < d;
    int s = valid ? list[n * CAP + lane] : 0;
    float a = a_src[s] + a_dst[n];
    a = a > 0.f ? a : 0.2f * a;
    float al = valid ? a : -INFINITY;
    float mh = al;
    #pragma unroll
    for (int m = 1; m < 64; m <<= 1) mh = fmaxf(mh, __shfl_xor(mh, m));
    float eh = valid ? __expf(al - mh) : 0.f;
    float sh = eh;
    #pragma unroll
    for (int m = 1; m < 64; m <<= 1) sh += __shfl_xor(sh, m);
    w_lds[wv][lane] = eh / (sh + 1e-16f);
    s_lds[wv][lane] = s;
    __syncthreads();

    float acc0 = 0.f, acc1 = 0.f;
    for (int e = 0; e < d; e++) {
        int ss = s_lds[wv][e];
        float w = w_lds[wv][e];
        acc0 = fmaf(w, h[ss * 128 + lane], acc0);
        acc1 = fmaf(w, h[ss * 128 + 64 + lane], acc1);
    }
    out[n * 128 + lane] = acc0 + bias[lane];
    out[n * 128 + 64 + lane] = acc1 + bias[64 + lane];
}

extern "C" void kernel_launch(void* const* d_in, const int* in_sizes, int n_in,
                              void* d_out, int out_size, void* d_ws, size_t ws_size,
                              hipStream_t stream)
{
    (void)in_sizes; (void)n_in; (void)out_size; (void)ws_size;
    const float* x   = (const float*)d_in[0];
    const int*   ei  = (const int*)d_in[1];
    const float* W1  = (const float*)d_in[2];
    const float* as1 = (const float*)d_in[3];
    const float* ad1 = (const float*)d_in[4];
    const float* b1  = (const float*)d_in[5];
    const float* W2  = (const float*)d_in[6];
    const float* as2 = (const float*)d_in[7];
    const float* ad2 = (const float*)d_in[8];
    const float* b2  = (const float*)d_in[9];
    float* out = (float*)d_out;
    const int* srcv = ei;
    const int* dstv = ei + N_EDGES;

    char* ws = (char*)d_ws;
    size_t off = 0;
    auto alloc = [&](size_t bytes) {
        void* p = ws + off;
        off += (bytes + 255) & ~(size_t)255;
        return p;
    };
    float* h1    = (float*)alloc((size_t)N_NODES * 128 * 4);
    float* h1b   = (float*)alloc((size_t)N_NODES * 128 * 4);
    float* asrc1 = (float*)alloc((size_t)N_NODES * 8 * 4);
    float* adst1 = (float*)alloc((size_t)N_NODES * 8 * 4);
    float* asrc2 = (float*)alloc((size_t)N_NODES * 4);
    float* adst2 = (float*)alloc((size_t)N_NODES * 4);
    int*   degp  = (int*)alloc((size_t)N_NODES * 4);
    int*   curp  = (int*)alloc((size_t)N_NODES * 4);
    int*   list  = (int*)alloc((size_t)N_NODES * CAP * 4);
    float* h2 = h1;   // reuse h1 after layer-1 aggregation

    hipMemsetAsync(degp, 0, (size_t)N_NODES * 4, stream);
    hipMemsetAsync(curp, 0, (size_t)N_NODES * 4, stream);

    const int EG = (N_EDGES + 255) / 256;          // 3125
    const int NG = (N_NODES + 3) / 4;              // 12500
    const int GG = ((N_NODES / 8) + 7) / 8;        // 782 blocks of 8 waves

    count_kernel<<<EG, 256, 0, stream>>>(dstv, degp);
    scatter_kernel<<<EG, 256, 0, stream>>>(srcv, dstv, curp, list);

    gemm128_kernel<<<GG, 512, 0, stream>>>(x, W1, h1, N_NODES);
    att1_kernel<<<NG, 256, 0, stream>>>(h1, as1, ad1, asrc1, adst1);
    agg1_kernel<<<NG, 256, 0, stream>>>(h1, list, degp, asrc1, adst1, b1, h1b);

    gemm128_kernel<<<GG, 512, 0, stream>>>(h1b, W2, h2, N_NODES);
    att2_kernel<<<NG, 256, 0, stream>>>(h2, as2, ad2, asrc2, adst2);
    agg2_kernel<<<NG, 256, 0, stream>>>(h2, list, degp, asrc2, adst2, b2, out);
}

// Round 2
// 271.407 us; speedup vs baseline: 1.2743x; 1.2743x over previous
//
#include <hip/hip_runtime.h>

#define N_NODES 50000
#define N_EDGES 800000
#define CAP 64

typedef unsigned int uint;
typedef unsigned short ushort;

__device__ __forceinline__ float readlane_f(float v, int l) {
    return __int_as_float(__builtin_amdgcn_readlane(__float_as_int(v), l));
}
__device__ __forceinline__ ushort f2bf(float f) {   // RTNE f32 -> bf16
    uint u = __float_as_uint(f);
    u = (u + 0x7fffu + ((u >> 16) & 1u)) >> 16;
    return (ushort)u;
}
__device__ __forceinline__ float bf_lo(uint u) { return __uint_as_float(u << 16); }
__device__ __forceinline__ float bf_hi(uint u) { return __uint_as_float(u & 0xffff0000u); }

// h16[N,128](bf16) = A[N,128] @ W[128,128]; fused per-head attention dots.
// Block = 512 thr = 8 waves, wave does 8 rows. HEADS in {8,1}; C = 128/HEADS.
template <int HEADS>
__global__ __launch_bounds__(512) void gemm_fused_kernel(
    const float* __restrict__ A, const float* __restrict__ W,
    const float* __restrict__ att_src, const float* __restrict__ att_dst,
    ushort* __restrict__ h16, float* __restrict__ a_src, float* __restrict__ a_dst,
    int nrows)
{
    __shared__ float2 Wl[128 * 64];   // Wl[k*64+c] = {W[k][c], W[k][c+64]}  (64 KB)
    int tid = threadIdx.x;
    for (int idx = tid; idx < 128 * 64; idx += 512) {
        int k = idx >> 6, c = idx & 63;
        Wl[idx] = make_float2(W[k * 128 + c], W[k * 128 + 64 + c]);
    }
    __syncthreads();
    int lane = tid & 63;
    int wave = (blockIdx.x << 3) + (tid >> 6);
    int row0 = wave << 3;
    if (row0 >= nrows) return;

    float asx = att_src[lane], asy = att_src[64 + lane];
    float adx = att_dst[lane], ady = att_dst[64 + lane];

    float x0[8], x1[8];
    #pragma unroll
    for (int r = 0; r < 8; r++) {
        x0[r] = A[(row0 + r) * 128 + lane];
        x1[r] = A[(row0 + r) * 128 + 64 + lane];
    }
    float2 acc[8];
    #pragma unroll
    for (int r = 0; r < 8; r++) acc[r] = make_float2(0.f, 0.f);

    for (int k = 0; k < 64; k++) {
        float2 wk = Wl[(k << 6) + lane];
        #pragma unroll
        for (int r = 0; r < 8; r++) {
            float xv = readlane_f(x0[r], k);
            acc[r].x = fmaf(xv, wk.x, acc[r].x);
            acc[r].y = fmaf(xv, wk.y, acc[r].y);
        }
    }
    for (int k = 0; k < 64; k++) {
        float2 wk = Wl[((64 + k) << 6) + lane];
        #pragma unroll
        for (int r = 0; r < 8; r++) {
            float xv = readlane_f(x1[r], k);
            acc[r].x = fmaf(xv, wk.x, acc[r].x);
            acc[r].y = fmaf(xv, wk.y, acc[r].y);
        }
    }

    #pragma unroll
    for (int r = 0; r < 8; r++) {
        int row = row0 + r;
        float ps0 = acc[r].x * asx, ps1 = acc[r].y * asy;
        float pd0 = acc[r].x * adx, pd1 = acc[r].y * ady;
        if (HEADS == 8) {
            #pragma unroll
            for (int m = 1; m < 16; m <<= 1) {
                ps0 += __shfl_xor(ps0, m); ps1 += __shfl_xor(ps1, m);
                pd0 += __shfl_xor(pd0, m); pd1 += __shfl_xor(pd1, m);
            }
            if ((lane & 15) == 0) {
                int g = lane >> 4;
                a_src[row * 8 + g] = ps0;  a_src[row * 8 + 4 + g] = ps1;
                a_dst[row * 8 + g] = pd0;  a_dst[row * 8 + 4 + g] = pd1;
            }
        } else {
            float ps = ps0 + ps1, pd = pd0 + pd1;
            #pragma unroll
            for (int m = 1; m < 64; m <<= 1) {
                ps += __shfl_xor(ps, m); pd += __shfl_xor(pd, m);
            }
            if (lane == 0) { a_src[row] = ps; a_dst[row] = pd; }
        }
        h16[row * 128 + lane] = f2bf(acc[r].x);
        h16[row * 128 + 64 + lane] = f2bf(acc[r].y);
    }
}

// Adjacency build: cursor ends up as degree.
__global__ __launch_bounds__(256) void scatter_kernel(
    const int* __restrict__ srcv, const int* __restrict__ dstv,
    int* __restrict__ cursor, int* __restrict__ list)
{
    int e = blockIdx.x * 256 + threadIdx.x;
    if (e < N_EDGES) {
        int d = dstv[e];
        int slot = atomicAdd(&cursor[d], 1);
        if (slot < CAP) list[d * CAP + slot] = srcv[e];
    }
}

// Edge softmax + aggregate (+ bias, optional ELU). Wave per node; h in bf16.
template <int HEADS, bool ELU>
__global__ __launch_bounds__(256) void agg_kernel(
    const ushort* __restrict__ h16, const int* __restrict__ list, const int* __restrict__ deg,
    const float* __restrict__ a_src, const float* __restrict__ a_dst,
    const float* __restrict__ bias, float* __restrict__ out)
{
    __shared__ float w_lds[4][64][HEADS];
    __shared__ int s_lds[4][64];
    int lane = threadIdx.x & 63;
    int wv = threadIdx.x >> 6;
    int n = blockIdx.x * 4 + wv;
    int d = min(deg[n], CAP);
    bool valid = lane < d;
    int s = valid ? list[n * CAP + lane] : 0;

    float al[HEADS];
    #pragma unroll
    for (int hh = 0; hh < HEADS; hh++) {
        float a = a_src[s * HEADS + hh] + a_dst[n * HEADS + hh];
        a = a > 0.f ? a : 0.2f * a;            // leaky_relu 0.2
        al[hh] = valid ? a : -INFINITY;
    }
    float mh[HEADS];
    #pragma unroll
    for (int hh = 0; hh < HEADS; hh++) mh[hh] = al[hh];
    #pragma unroll
    for (int m = 1; m < 64; m <<= 1) {
        #pragma unroll
        for (int hh = 0; hh < HEADS; hh++) mh[hh] = fmaxf(mh[hh], __shfl_xor(mh[hh], m));
    }
    float eh[HEADS], sh[HEADS];
    #pragma unroll
    for (int hh = 0; hh < HEADS; hh++) {
        eh[hh] = valid ? __expf(al[hh] - mh[hh]) : 0.f;
        sh[hh] = eh[hh];
    }
    #pragma unroll
    for (int m = 1; m < 64; m <<= 1) {
        #pragma unroll
        for (int hh = 0; hh < HEADS; hh++) sh[hh] += __shfl_xor(sh[hh], m);
    }
    #pragma unroll
    for (int hh = 0; hh < HEADS; hh++) w_lds[wv][lane][hh] = eh[hh] / (sh[hh] + 1e-16f);
    s_lds[wv][lane] = s;
    __syncthreads();

    // lane covers channels c0, c0+1 (same head: g = lane>>3 when HEADS=8).
    int c0 = lane << 1;
    int g = (HEADS == 8) ? (lane >> 3) : 0;
    float acc0 = 0.f, acc1 = 0.f;
    int e = 0;
    for (; e + 4 <= d; e += 4) {
        int s0 = s_lds[wv][e],     s1 = s_lds[wv][e + 1];
        int s2 = s_lds[wv][e + 2], s3 = s_lds[wv][e + 3];
        uint u0 = *(const uint*)&h16[s0 * 128 + c0];
        uint u1 = *(const uint*)&h16[s1 * 128 + c0];
        uint u2 = *(const uint*)&h16[s2 * 128 + c0];
        uint u3 = *(const uint*)&h16[s3 * 128 + c0];
        float w0 = w_lds[wv][e][g],     w1 = w_lds[wv][e + 1][g];
        float w2 = w_lds[wv][e + 2][g], w3 = w_lds[wv][e + 3][g];
        acc0 = fmaf(w0, bf_lo(u0), acc0); acc1 = fmaf(w0, bf_hi(u0), acc1);
        acc0 = fmaf(w1, bf_lo(u1), acc0); acc1 = fmaf(w1, bf_hi(u1), acc1);
        acc0 = fmaf(w2, bf_lo(u2), acc0); acc1 = fmaf(w2, bf_hi(u2), acc1);
        acc0 = fmaf(w3, bf_lo(u3), acc0); acc1 = fmaf(w3, bf_hi(u3), acc1);
    }
    for (; e < d; e++) {
        int ss = s_lds[wv][e];
        uint u = *(const uint*)&h16[ss * 128 + c0];
        float w = w_lds[wv][e][g];
        acc0 = fmaf(w, bf_lo(u), acc0);
        acc1 = fmaf(w, bf_hi(u), acc1);
    }
    float o0 = acc0 + bias[c0];
    float o1 = acc1 + bias[c0 + 1];
    if (ELU) {
        o0 = o0 > 0.f ? o0 : __expf(o0) - 1.f;
        o1 = o1 > 0.f ? o1 : __expf(o1) - 1.f;
    }
    *(float2*)&out[n * 128 + c0] = make_float2(o0, o1);
}

extern "C" void kernel_launch(void* const* d_in, const int* in_sizes, int n_in,
                              void* d_out, int out_size, void* d_ws, size_t ws_size,
                              hipStream_t stream)
{
    (void)in_sizes; (void)n_in; (void)out_size; (void)ws_size;
    const float* x   = (const float*)d_in[0];
    const int*   ei  = (const int*)d_in[1];
    const float* W1  = (const float*)d_in[2];
    const float* as1 = (const float*)d_in[3];
    const float* ad1 = (const float*)d_in[4];
    const float* b1  = (const float*)d_in[5];
    const float* W2  = (const float*)d_in[6];
    const float* as2 = (const float*)d_in[7];
    const float* ad2 = (const float*)d_in[8];
    const float* b2  = (const float*)d_in[9];
    float* out = (float*)d_out;
    const int* srcv = ei;
    const int* dstv = ei + N_EDGES;

    char* ws = (char*)d_ws;
    size_t off = 0;
    auto alloc = [&](size_t bytes) {
        void* p = ws + off;
        off += (bytes + 255) & ~(size_t)255;
        return p;
    };
    ushort* h1_16 = (ushort*)alloc((size_t)N_NODES * 128 * 2);
    ushort* h2_16 = (ushort*)alloc((size_t)N_NODES * 128 * 2);
    float*  h1b   = (float*)alloc((size_t)N_NODES * 128 * 4);
    float*  asrc1 = (float*)alloc((size_t)N_NODES * 8 * 4);
    float*  adst1 = (float*)alloc((size_t)N_NODES * 8 * 4);
    float*  asrc2 = (float*)alloc((size_t)N_NODES * 4);
    float*  adst2 = (float*)alloc((size_t)N_NODES * 4);
    int*    curp  = (int*)alloc((size_t)N_NODES * 4);
    int*    list  = (int*)alloc((size_t)N_NODES * CAP * 4);

    hipMemsetAsync(curp, 0, (size_t)N_NODES * 4, stream);

    const int EG = (N_EDGES + 255) / 256;          // 3125
    const int NG = (N_NODES + 3) / 4;              // 12500
    const int GG = ((N_NODES / 8) + 7) / 8;        // 782 blocks of 8 waves

    scatter_kernel<<<EG, 256, 0, stream>>>(srcv, dstv, curp, list);

    gemm_fused_kernel<8><<<GG, 512, 0, stream>>>(x, W1, as1, ad1, h1_16, asrc1, adst1, N_NODES);
    agg_kernel<8, true><<<NG, 256, 0, stream>>>(h1_16, list, curp, asrc1, adst1, b1, h1b);

    gemm_fused_kernel<1><<<GG, 512, 0, stream>>>(h1b, W2, as2, ad2, h2_16, asrc2, adst2, N_NODES);
    agg_kernel<1, false><<<NG, 256, 0, stream>>>(h2_16, list, curp, asrc2, adst2, b2, out);
}

// Round 3
// 155.960 us; speedup vs baseline: 2.2176x; 1.7402x over previous
//
#include <hip/hip_runtime.h>

#define N_NODES 50000
#define N_EDGES 800000
#define CAP 64

typedef unsigned int uint;
typedef unsigned short ushort;
typedef __attribute__((ext_vector_type(4))) float f32x4;
typedef __attribute__((ext_vector_type(8))) short s16x8;

__device__ __forceinline__ ushort f2bf(float f) {   // RTNE f32 -> bf16
    uint u = __float_as_uint(f);
    u = (u + 0x7fffu + ((u >> 16) & 1u)) >> 16;
    return (ushort)u;
}
__device__ __forceinline__ float bf_lo(uint u) { return __uint_as_float(u << 16); }
__device__ __forceinline__ float bf_hi(uint u) { return __uint_as_float(u & 0xffff0000u); }

// ---------------- adjacency build (cursor ends as degree) ----------------
__global__ __launch_bounds__(256) void scatter_kernel(
    const int* __restrict__ srcv, const int* __restrict__ dstv,
    int* __restrict__ cursor, int* __restrict__ list)
{
    int e = blockIdx.x * 256 + threadIdx.x;
    if (e < N_EDGES) {
        int dd = dstv[e];
        int slot = atomicAdd(&cursor[dd], 1);
        if (slot < CAP) list[dd * CAP + slot] = srcv[e];
    }
}

// ---------------- WS = W @ S  (fold attention dots into GEMM) ----------------
// WS1[k][j]: j<8 -> sum_{c<16} W1[k][j*16+c]*as1[j*16+c]; j>=8 -> with ad1.
// WS2[k][0] = sum_c W2[k][c]*as2[c]; WS2[k][1] with ad2; cols 2..15 = 0.
__global__ __launch_bounds__(256) void prep_kernel(
    const float* __restrict__ W1, const float* __restrict__ as1, const float* __restrict__ ad1,
    const float* __restrict__ W2, const float* __restrict__ as2, const float* __restrict__ ad2,
    float* __restrict__ WS1, float* __restrict__ WS2)
{
    int idx = blockIdx.x * 256 + threadIdx.x;
    if (idx < 2048) {
        int k = idx >> 4, j = idx & 15;
        const float* att = (j < 8) ? as1 : ad1;
        int head = j & 7;
        float s = 0.f;
        #pragma unroll
        for (int c = 0; c < 16; c++)
            s += W1[k * 128 + head * 16 + c] * att[head * 16 + c];
        WS1[idx] = s;
    } else if (idx < 4096) {
        int idx2 = idx - 2048;
        int k = idx2 >> 4, j = idx2 & 15;
        float s = 0.f;
        if (j < 2) {
            const float* att = j ? ad2 : as2;
            for (int c = 0; c < 128; c++) s += W2[k * 128 + c] * att[c];
        }
        WS2[idx2] = s;
    }
}

// ---------------- MFMA GEMM: h16 = bf16(A @ W), logits fused as 9th tile ----------------
// Block 512 = 8 waves; wave does 16 rows x 128 cols (+16 logit cols). K = 128.
template <int HEADS>
__global__ __launch_bounds__(512) void gemm_mfma_kernel(
    const float* __restrict__ A, const float* __restrict__ W,
    const float* __restrict__ WS,
    ushort* __restrict__ h16, float* __restrict__ a_src, float* __restrict__ a_dst,
    int nrows)
{
    __shared__ ushort Bf[2304 * 8];   // 36 KB: frag slot = (t*4+kt)*64 + lane, 8 bf16 each
    int tid = threadIdx.x;
    for (int idx = tid; idx < 2304; idx += 512) {
        int t = idx >> 8;             // col-tile 0..8
        int rem = idx & 255;
        int kt = rem >> 6, L = rem & 63;
        int col = L & 15;
        int kb = ((L >> 4) << 3) + (kt << 5);   // k base for this lane's 8 elems
        ushort tmp[8];
        if (t < 8) {
            #pragma unroll
            for (int j = 0; j < 8; j++)
                tmp[j] = f2bf(W[(size_t)(kb + j) * 128 + (t << 4) + col]);
        } else {
            #pragma unroll
            for (int j = 0; j < 8; j++)
                tmp[j] = f2bf(WS[(kb + j) * 16 + col]);
        }
        uint p0 = (uint)tmp[0] | ((uint)tmp[1] << 16);
        uint p1 = (uint)tmp[2] | ((uint)tmp[3] << 16);
        uint p2 = (uint)tmp[4] | ((uint)tmp[5] << 16);
        uint p3 = (uint)tmp[6] | ((uint)tmp[7] << 16);
        uint4 pk = make_uint4(p0, p1, p2, p3);
        *(uint4*)&Bf[idx * 8] = pk;
    }
    __syncthreads();

    int lane = tid & 63;
    int wv = tid >> 6;
    int row0 = (blockIdx.x * 8 + wv) * 16;
    if (row0 >= nrows) return;

    int m = lane & 15, kg = lane >> 4;
    const float* arow = A + (size_t)(row0 + m) * 128 + (kg << 3);

    s16x8 afrag[4];
    #pragma unroll
    for (int kt = 0; kt < 4; kt++) {
        float4 f0 = *(const float4*)(arow + (kt << 5));
        float4 f1 = *(const float4*)(arow + (kt << 5) + 4);
        union { s16x8 v; ushort us[8]; } uu;
        uu.us[0] = f2bf(f0.x); uu.us[1] = f2bf(f0.y);
        uu.us[2] = f2bf(f0.z); uu.us[3] = f2bf(f0.w);
        uu.us[4] = f2bf(f1.x); uu.us[5] = f2bf(f1.y);
        uu.us[6] = f2bf(f1.z); uu.us[7] = f2bf(f1.w);
        afrag[kt] = uu.v;
    }

    f32x4 acc[9];
    #pragma unroll
    for (int t = 0; t < 9; t++) acc[t] = (f32x4){0.f, 0.f, 0.f, 0.f};

    #pragma unroll
    for (int t = 0; t < 9; t++) {
        #pragma unroll
        for (int kt = 0; kt < 4; kt++) {
            s16x8 b = *(const s16x8*)&Bf[(((t << 2) + kt) * 64 + lane) * 8];
            acc[t] = __builtin_amdgcn_mfma_f32_16x16x32_bf16(afrag[kt], b, acc[t], 0, 0, 0);
        }
    }

    // epilogue: D layout col = lane&15, row = (lane>>4)*4 + r   [m89]
    int colw = lane & 15;
    int rbase = row0 + ((lane >> 4) << 2);
    #pragma unroll
    for (int t = 0; t < 8; t++) {
        #pragma unroll
        for (int r = 0; r < 4; r++)
            h16[(size_t)(rbase + r) * 128 + (t << 4) + colw] = f2bf(acc[t][r]);
    }
    #pragma unroll
    for (int r = 0; r < 4; r++) {
        float v = acc[8][r];
        int row = rbase + r;
        if (HEADS == 8) {
            if (colw < 8) a_src[row * 8 + colw] = v;
            else          a_dst[row * 8 + (colw - 8)] = v;
        } else {
            if (colw == 0)      a_src[row] = v;
            else if (colw == 1) a_dst[row] = v;
        }
    }
}

// ---------------- edge softmax + aggregate. Wave per node; 16-deep prefetch ----------------
template <int HEADS, bool ELU>
__global__ __launch_bounds__(256) void agg_kernel(
    const ushort* __restrict__ h16, const int* __restrict__ list, const int* __restrict__ deg,
    const float* __restrict__ a_src, const float* __restrict__ a_dst,
    const float* __restrict__ bias, float* __restrict__ out)
{
    __shared__ float w_lds[4][HEADS][65];   // padded: conflict-free strided read
    __shared__ int s_lds[4][64];
    int lane = threadIdx.x & 63;
    int wv = threadIdx.x >> 6;
    int n = blockIdx.x * 4 + wv;
    int d = min(deg[n], CAP);
    bool valid = lane < d;
    int s = valid ? list[n * CAP + lane] : 0;
    s_lds[wv][lane] = s;

    // logits: no max-subtraction (shift-invariant; |logit| is O(3), no overflow risk)
    float eh[HEADS], sh[HEADS];
    if (HEADS == 8) {
        float4 u0 = *(const float4*)&a_src[s * 8];
        float4 u1 = *(const float4*)&a_src[s * 8 + 4];
        float4 v0 = *(const float4*)&a_dst[n * 8];
        float4 v1 = *(const float4*)&a_dst[n * 8 + 4];
        float al[8] = {u0.x + v0.x, u0.y + v0.y, u0.z + v0.z, u0.w + v0.w,
                       u1.x + v1.x, u1.y + v1.y, u1.z + v1.z, u1.w + v1.w};
        #pragma unroll
        for (int hh = 0; hh < 8; hh++) {
            float a = al[hh];
            a = a > 0.f ? a : 0.2f * a;          // leaky_relu 0.2
            eh[hh] = valid ? __expf(a) : 0.f;
            sh[hh] = eh[hh];
        }
    } else {
        float a = a_src[s] + a_dst[n];
        a = a > 0.f ? a : 0.2f * a;
        eh[0] = valid ? __expf(a) : 0.f;
        sh[0] = eh[0];
    }
    // adaptive-depth butterfly sum (invalid lanes contribute 0; their w ends 0)
    #pragma unroll
    for (int mm = 1; mm < 16; mm <<= 1) {
        #pragma unroll
        for (int hh = 0; hh < HEADS; hh++) sh[hh] += __shfl_xor(sh[hh], mm);
    }
    if (d > 16) {
        #pragma unroll
        for (int hh = 0; hh < HEADS; hh++) sh[hh] += __shfl_xor(sh[hh], 16);
    }
    if (d > 32) {
        #pragma unroll
        for (int hh = 0; hh < HEADS; hh++) sh[hh] += __shfl_xor(sh[hh], 32);
    }
    #pragma unroll
    for (int hh = 0; hh < HEADS; hh++)
        w_lds[wv][hh][lane] = eh[hh] / (sh[hh] + 1e-16f);
    __syncthreads();

    // gather: lane covers channels c0, c0+1; 16 loads in flight per chunk
    int c0 = lane << 1;
    int g = (HEADS == 8) ? (lane >> 3) : 0;
    const ushort* hbase = h16 + c0;
    float acc0 = 0.f, acc1 = 0.f;
    int d16 = (d + 15) & ~15;
    for (int e0 = 0; e0 < d16; e0 += 16) {
        uint u[16]; float w[16];
        #pragma unroll
        for (int j = 0; j < 16; j++) {
            int ss = s_lds[wv][e0 + j];
            u[j] = *(const uint*)(hbase + (size_t)ss * 128);
            w[j] = w_lds[wv][g][e0 + j];
        }
        #pragma unroll
        for (int j = 0; j < 16; j++) {
            acc0 = fmaf(w[j], bf_lo(u[j]), acc0);
            acc1 = fmaf(w[j], bf_hi(u[j]), acc1);
        }
    }
    float o0 = acc0 + bias[c0];
    float o1 = acc1 + bias[c0 + 1];
    if (ELU) {
        o0 = o0 > 0.f ? o0 : __expf(o0) - 1.f;
        o1 = o1 > 0.f ? o1 : __expf(o1) - 1.f;
    }
    *(float2*)&out[n * 128 + c0] = make_float2(o0, o1);
}

extern "C" void kernel_launch(void* const* d_in, const int* in_sizes, int n_in,
                              void* d_out, int out_size, void* d_ws, size_t ws_size,
                              hipStream_t stream)
{
    (void)in_sizes; (void)n_in; (void)out_size; (void)ws_size;
    const float* x   = (const float*)d_in[0];
    const int*   ei  = (const int*)d_in[1];
    const float* W1  = (const float*)d_in[2];
    const float* as1 = (const float*)d_in[3];
    const float* ad1 = (const float*)d_in[4];
    const float* b1  = (const float*)d_in[5];
    const float* W2  = (const float*)d_in[6];
    const float* as2 = (const float*)d_in[7];
    const float* ad2 = (const float*)d_in[8];
    const float* b2  = (const float*)d_in[9];
    float* out = (float*)d_out;
    const int* srcv = ei;
    const int* dstv = ei + N_EDGES;

    char* ws = (char*)d_ws;
    size_t off = 0;
    auto alloc = [&](size_t bytes) {
        void* p = ws + off;
        off += (bytes + 255) & ~(size_t)255;
        return p;
    };
    ushort* h1_16 = (ushort*)alloc((size_t)N_NODES * 128 * 2);
    ushort* h2_16 = (ushort*)alloc((size_t)N_NODES * 128 * 2);
    float*  h1b   = (float*)alloc((size_t)N_NODES * 128 * 4);
    float*  asrc1 = (float*)alloc((size_t)N_NODES * 8 * 4);
    float*  adst1 = (float*)alloc((size_t)N_NODES * 8 * 4);
    float*  asrc2 = (float*)alloc((size_t)N_NODES * 4);
    float*  adst2 = (float*)alloc((size_t)N_NODES * 4);
    int*    curp  = (int*)alloc((size_t)N_NODES * 4);
    int*    list  = (int*)alloc((size_t)N_NODES * CAP * 4);
    float*  WS1   = (float*)alloc(128 * 16 * 4);
    float*  WS2   = (float*)alloc(128 * 16 * 4);

    hipMemsetAsync(curp, 0, (size_t)N_NODES * 4, stream);

    const int EG = (N_EDGES + 255) / 256;          // 3125
    const int NG = (N_NODES + 3) / 4;              // 12500
    const int GB = (N_NODES / 16 + 7) / 8;         // 391 blocks of 8 waves

    scatter_kernel<<<EG, 256, 0, stream>>>(srcv, dstv, curp, list);
    prep_kernel<<<16, 256, 0, stream>>>(W1, as1, ad1, W2, as2, ad2, WS1, WS2);

    gemm_mfma_kernel<8><<<GB, 512, 0, stream>>>(x, W1, WS1, h1_16, asrc1, adst1, N_NODES);
    agg_kernel<8, true><<<NG, 256, 0, stream>>>(h1_16, list, curp, asrc1, adst1, b1, h1b);

    gemm_mfma_kernel<1><<<GB, 512, 0, stream>>>(h1b, W2, WS2, h2_16, asrc2, adst2, N_NODES);
    agg_kernel<1, false><<<NG, 256, 0, stream>>>(h2_16, list, curp, asrc2, adst2, b2, out);
}

// Round 4
// 145.711 us; speedup vs baseline: 2.3736x; 1.0703x over previous
//
#include <hip/hip_runtime.h>

#define N_NODES 50000
#define N_EDGES 800000
#define CAP 64
#define NBUCK 196          // ceil(50000/256)
#define NODES_PAD 50176    // NBUCK*256
#define BBLK 256           // bin blocks
#define EPB 3125           // edges per bin block (800000/256)

typedef unsigned int uint;
typedef unsigned short ushort;
typedef __attribute__((ext_vector_type(4))) float f32x4;
typedef __attribute__((ext_vector_type(8))) short s16x8;

__device__ __forceinline__ ushort f2bf(float f) {   // RTNE f32 -> bf16
    uint u = __float_as_uint(f);
    u = (u + 0x7fffu + ((u >> 16) & 1u)) >> 16;
    return (ushort)u;
}
__device__ __forceinline__ float bf_lo(uint u) { return __uint_as_float(u << 16); }
__device__ __forceinline__ float bf_hi(uint u) { return __uint_as_float(u & 0xffff0000u); }

// ---------------- binned adjacency build ----------------
__global__ __launch_bounds__(256) void bin_count_kernel(
    const int* __restrict__ dstv, uint* __restrict__ counts)
{
    __shared__ uint hist[NBUCK];
    int tid = threadIdx.x, b = blockIdx.x;
    for (int k = tid; k < NBUCK; k += 256) hist[k] = 0;
    __syncthreads();
    int e0 = b * EPB;
    for (int i = tid; i < EPB; i += 256)
        atomicAdd(&hist[((uint)dstv[e0 + i]) >> 8], 1u);
    __syncthreads();
    for (int k = tid; k < NBUCK; k += 256) counts[k * BBLK + b] = hist[k];
}

// one block: flat exclusive scan of counts[50176] -> ofs[50177]
__global__ __launch_bounds__(256) void scan_kernel(
    const uint* __restrict__ counts, uint* __restrict__ ofs)
{
    __shared__ uint wsum[4];
    int tid = threadIdx.x;
    int lane = tid & 63, wid = tid >> 6;
    int base = tid * NBUCK;                 // 256 chunks of 196 = 50176
    uint s = 0;
    for (int i = 0; i < NBUCK; i++) s += counts[base + i];
    uint inc = s;
    #pragma unroll
    for (int o = 1; o < 64; o <<= 1) {
        uint v = __shfl_up(inc, o);
        if (lane >= o) inc += v;
    }
    if (lane == 63) wsum[wid] = inc;
    __syncthreads();
    uint wo = 0;
    for (int w = 0; w < wid; w++) wo += wsum[w];
    uint off = wo + inc - s;                // exclusive prefix for this chunk
    for (int i = 0; i < NBUCK; i++) {
        uint v = counts[base + i];
        ofs[base + i] = off;
        off += v;
    }
    if (tid == 255) ofs[NODES_PAD] = off;   // total = N_EDGES
}

__global__ __launch_bounds__(256) void bin_scatter_kernel(
    const int* __restrict__ srcv, const int* __restrict__ dstv,
    const uint* __restrict__ ofs, uint* __restrict__ binned)
{
    __shared__ uint cur[NBUCK];
    int tid = threadIdx.x, b = blockIdx.x;
    for (int k = tid; k < NBUCK; k += 256) cur[k] = ofs[k * BBLK + b];
    __syncthreads();
    int e0 = b * EPB;
    for (int i = tid; i < EPB; i += 256) {
        int d = dstv[e0 + i], s = srcv[e0 + i];
        uint k = ((uint)d) >> 8;
        uint pos = atomicAdd(&cur[k], 1u);
        binned[pos] = (((uint)d & 255u) << 16) | (uint)s;
    }
}

// block per bucket: LDS-staged per-node lists, dense coalesced writeback
__global__ __launch_bounds__(256) void build_kernel(
    const uint* __restrict__ binned, const uint* __restrict__ ofs,
    int* __restrict__ deg, int* __restrict__ list)
{
    __shared__ uint ldeg[256];
    __shared__ uint llist[256 * CAP];       // 64 KB
    int tid = threadIdx.x, k = blockIdx.x;
    ldeg[tid] = 0;
    __syncthreads();
    uint start = ofs[k * BBLK];
    uint end = ofs[(k + 1) * BBLK];
    for (uint i = start + tid; i < end; i += 256) {
        uint p = binned[i];
        uint nl = (p >> 16) & 255u;
        uint slot = atomicAdd(&ldeg[nl], 1u);
        if (slot < CAP) llist[(nl << 6) + slot] = p & 0xFFFFu;
    }
    __syncthreads();
    int node0 = k << 8;
    deg[node0 + tid] = (int)ldeg[tid];
    uint4* d4 = (uint4*)(list + (size_t)node0 * CAP);
    const uint4* s4 = (const uint4*)llist;
    for (int i = tid; i < 256 * CAP / 4; i += 256) d4[i] = s4[i];
}

// ---------------- WS = W @ S  (fold attention dots into GEMM) ----------------
__global__ __launch_bounds__(256) void prep_kernel(
    const float* __restrict__ W1, const float* __restrict__ as1, const float* __restrict__ ad1,
    const float* __restrict__ W2, const float* __restrict__ as2, const float* __restrict__ ad2,
    float* __restrict__ WS1, float* __restrict__ WS2)
{
    int idx = blockIdx.x * 256 + threadIdx.x;
    if (idx < 2048) {
        int k = idx >> 4, j = idx & 15;
        const float* att = (j < 8) ? as1 : ad1;
        int head = j & 7;
        float s = 0.f;
        #pragma unroll
        for (int c = 0; c < 16; c++)
            s += W1[k * 128 + head * 16 + c] * att[head * 16 + c];
        WS1[idx] = s;
    } else if (idx < 4096) {
        int idx2 = idx - 2048;
        int k = idx2 >> 4, j = idx2 & 15;
        float s = 0.f;
        if (j < 2) {
            const float* att = j ? ad2 : as2;
            for (int c = 0; c < 128; c++) s += W2[k * 128 + c] * att[c];
        }
        WS2[idx2] = s;
    }
}

// ---------------- MFMA GEMM: h16 = bf16(A @ W), logits fused as 9th tile ----------------
// Block 512 = 8 waves; wave does 16 rows x 128 cols (+16 logit cols). K = 128.
template <int HEADS, bool ABF16>
__global__ __launch_bounds__(512) void gemm_mfma_kernel(
    const void* __restrict__ Av, const float* __restrict__ W,
    const float* __restrict__ WS,
    ushort* __restrict__ h16, float* __restrict__ a_src, float* __restrict__ a_dst,
    int nrows)
{
    __shared__ ushort Bf[2304 * 8];   // 36 KB: frag slot = (t*4+kt)*64 + lane
    int tid = threadIdx.x;
    for (int idx = tid; idx < 2304; idx += 512) {
        int t = idx >> 8;             // col-tile 0..8
        int rem = idx & 255;
        int kt = rem >> 6, L = rem & 63;
        int col = L & 15;
        int kb = ((L >> 4) << 3) + (kt << 5);
        ushort tmp[8];
        if (t < 8) {
            #pragma unroll
            for (int j = 0; j < 8; j++)
                tmp[j] = f2bf(W[(size_t)(kb + j) * 128 + (t << 4) + col]);
        } else {
            #pragma unroll
            for (int j = 0; j < 8; j++)
                tmp[j] = f2bf(WS[(kb + j) * 16 + col]);
        }
        uint p0 = (uint)tmp[0] | ((uint)tmp[1] << 16);
        uint p1 = (uint)tmp[2] | ((uint)tmp[3] << 16);
        uint p2 = (uint)tmp[4] | ((uint)tmp[5] << 16);
        uint p3 = (uint)tmp[6] | ((uint)tmp[7] << 16);
        *(uint4*)&Bf[idx * 8] = make_uint4(p0, p1, p2, p3);
    }
    __syncthreads();

    int lane = tid & 63;
    int wv = tid >> 6;
    int row0 = (blockIdx.x * 8 + wv) * 16;
    if (row0 >= nrows) return;

    int m = lane & 15, kg = lane >> 4;
    s16x8 afrag[4];
    if (ABF16) {
        const ushort* arow = (const ushort*)Av + (size_t)(row0 + m) * 128 + (kg << 3);
        #pragma unroll
        for (int kt = 0; kt < 4; kt++)
            afrag[kt] = *(const s16x8*)(arow + (kt << 5));
    } else {
        const float* arow = (const float*)Av + (size_t)(row0 + m) * 128 + (kg << 3);
        #pragma unroll
        for (int kt = 0; kt < 4; kt++) {
            float4 f0 = *(const float4*)(arow + (kt << 5));
            float4 f1 = *(const float4*)(arow + (kt << 5) + 4);
            union { s16x8 v; ushort us[8]; } uu;
            uu.us[0] = f2bf(f0.x); uu.us[1] = f2bf(f0.y);
            uu.us[2] = f2bf(f0.z); uu.us[3] = f2bf(f0.w);
            uu.us[4] = f2bf(f1.x); uu.us[5] = f2bf(f1.y);
            uu.us[6] = f2bf(f1.z); uu.us[7] = f2bf(f1.w);
            afrag[kt] = uu.v;
        }
    }

    f32x4 acc[9];
    #pragma unroll
    for (int t = 0; t < 9; t++) acc[t] = (f32x4){0.f, 0.f, 0.f, 0.f};
    #pragma unroll
    for (int t = 0; t < 9; t++) {
        #pragma unroll
        for (int kt = 0; kt < 4; kt++) {
            s16x8 b = *(const s16x8*)&Bf[(((t << 2) + kt) * 64 + lane) * 8];
            acc[t] = __builtin_amdgcn_mfma_f32_16x16x32_bf16(afrag[kt], b, acc[t], 0, 0, 0);
        }
    }

    // D layout: col = lane&15, row = (lane>>4)*4 + r   [m89]
    int colw = lane & 15;
    int rbase = row0 + ((lane >> 4) << 2);
    #pragma unroll
    for (int t = 0; t < 8; t++) {
        #pragma unroll
        for (int r = 0; r < 4; r++)
            h16[(size_t)(rbase + r) * 128 + (t << 4) + colw] = f2bf(acc[t][r]);
    }
    #pragma unroll
    for (int r = 0; r < 4; r++) {
        float v = acc[8][r];
        int row = rbase + r;
        if (HEADS == 8) {
            if (colw < 8) a_src[row * 8 + colw] = v;
            else          a_dst[row * 8 + (colw - 8)] = v;
        } else {
            if (colw == 0)      a_src[row] = v;
            else if (colw == 1) a_dst[row] = v;
        }
    }
}

// ---------------- edge softmax + aggregate. Wave per node; 16-deep prefetch ----------------
template <int HEADS, bool ELU, bool OUT16>
__global__ __launch_bounds__(256) void agg_kernel(
    const ushort* __restrict__ h16, const int* __restrict__ list, const int* __restrict__ deg,
    const float* __restrict__ a_src, const float* __restrict__ a_dst,
    const float* __restrict__ bias, void* __restrict__ outv)
{
    __shared__ float w_lds[4][HEADS][65];
    __shared__ int s_lds[4][64];
    int lane = threadIdx.x & 63;
    int wv = threadIdx.x >> 6;
    int n = blockIdx.x * 4 + wv;
    int d = min(deg[n], CAP);
    bool valid = lane < d;
    int s = valid ? list[n * CAP + lane] : 0;
    s_lds[wv][lane] = s;

    float eh[HEADS], sh[HEADS];
    if (HEADS == 8) {
        float4 u0 = *(const float4*)&a_src[s * 8];
        float4 u1 = *(const float4*)&a_src[s * 8 + 4];
        float4 v0 = *(const float4*)&a_dst[n * 8];
        float4 v1 = *(const float4*)&a_dst[n * 8 + 4];
        float al[8] = {u0.x + v0.x, u0.y + v0.y, u0.z + v0.z, u0.w + v0.w,
                       u1.x + v1.x, u1.y + v1.y, u1.z + v1.z, u1.w + v1.w};
        #pragma unroll
        for (int hh = 0; hh < 8; hh++) {
            float a = al[hh];
            a = a > 0.f ? a : 0.2f * a;          // leaky_relu 0.2
            eh[hh] = valid ? __expf(a) : 0.f;
            sh[hh] = eh[hh];
        }
    } else {
        float a = a_src[s] + a_dst[n];
        a = a > 0.f ? a : 0.2f * a;
        eh[0] = valid ? __expf(a) : 0.f;
        sh[0] = eh[0];
    }
    #pragma unroll
    for (int mm = 1; mm < 16; mm <<= 1) {
        #pragma unroll
        for (int hh = 0; hh < HEADS; hh++) sh[hh] += __shfl_xor(sh[hh], mm);
    }
    if (d > 16) {
        #pragma unroll
        for (int hh = 0; hh < HEADS; hh++) sh[hh] += __shfl_xor(sh[hh], 16);
    }
    if (d > 32) {
        #pragma unroll
        for (int hh = 0; hh < HEADS; hh++) sh[hh] += __shfl_xor(sh[hh], 32);
    }
    #pragma unroll
    for (int hh = 0; hh < HEADS; hh++)
        w_lds[wv][hh][lane] = eh[hh] / (sh[hh] + 1e-16f);
    __syncthreads();

    int c0 = lane << 1;
    int g = (HEADS == 8) ? (lane >> 3) : 0;
    const ushort* hbase = h16 + c0;
    float acc0 = 0.f, acc1 = 0.f;
    int d16 = (d + 15) & ~15;
    for (int e0 = 0; e0 < d16; e0 += 16) {
        uint u[16]; float w[16];
        #pragma unroll
        for (int j = 0; j < 16; j++) {
            int ss = s_lds[wv][e0 + j];
            u[j] = *(const uint*)(hbase + (size_t)ss * 128);
            w[j] = w_lds[wv][g][e0 + j];
        }
        #pragma unroll
        for (int j = 0; j < 16; j++) {
            acc0 = fmaf(w[j], bf_lo(u[j]), acc0);
            acc1 = fmaf(w[j], bf_hi(u[j]), acc1);
        }
    }
    float o0 = acc0 + bias[c0];
    float o1 = acc1 + bias[c0 + 1];
    if (ELU) {
        o0 = o0 > 0.f ? o0 : __expf(o0) - 1.f;
        o1 = o1 > 0.f ? o1 : __expf(o1) - 1.f;
    }
    if (OUT16) {
        uint pk = (uint)f2bf(o0) | ((uint)f2bf(o1) << 16);
        *(uint*)((ushort*)outv + (size_t)n * 128 + c0) = pk;
    } else {
        *(float2*)((float*)outv + (size_t)n * 128 + c0) = make_float2(o0, o1);
    }
}

extern "C" void kernel_launch(void* const* d_in, const int* in_sizes, int n_in,
                              void* d_out, int out_size, void* d_ws, size_t ws_size,
                              hipStream_t stream)
{
    (void)in_sizes; (void)n_in; (void)out_size; (void)ws_size;
    const float* x   = (const float*)d_in[0];
    const int*   ei  = (const int*)d_in[1];
    const float* W1  = (const float*)d_in[2];
    const float* as1 = (const float*)d_in[3];
    const float* ad1 = (const float*)d_in[4];
    const float* b1  = (const float*)d_in[5];
    const float* W2  = (const float*)d_in[6];
    const float* as2 = (const float*)d_in[7];
    const float* ad2 = (const float*)d_in[8];
    const float* b2  = (const float*)d_in[9];
    float* out = (float*)d_out;
    const int* srcv = ei;
    const int* dstv = ei + N_EDGES;

    char* ws = (char*)d_ws;
    size_t off = 0;
    auto alloc = [&](size_t bytes) {
        void* p = ws + off;
        off += (bytes + 255) & ~(size_t)255;
        return p;
    };
    ushort* h1_16 = (ushort*)alloc((size_t)N_NODES * 128 * 2);
    ushort* h2_16 = (ushort*)alloc((size_t)N_NODES * 128 * 2);
    ushort* h1b   = (ushort*)alloc((size_t)N_NODES * 128 * 2);   // bf16 inter-layer act
    float*  asrc1 = (float*)alloc((size_t)N_NODES * 8 * 4);
    float*  adst1 = (float*)alloc((size_t)N_NODES * 8 * 4);
    float*  asrc2 = (float*)alloc((size_t)N_NODES * 4);
    float*  adst2 = (float*)alloc((size_t)N_NODES * 4);
    int*    degp  = (int*)alloc((size_t)NODES_PAD * 4);
    int*    list  = (int*)alloc((size_t)NODES_PAD * CAP * 4);
    float*  WS1   = (float*)alloc(128 * 16 * 4);
    float*  WS2   = (float*)alloc(128 * 16 * 4);
    // bin scratch aliases into h1b (consumed before agg1 writes h1b)
    uint* binned = (uint*)h1b;                       // 3.2 MB
    uint* counts = binned + N_EDGES;                 // 200 KB
    uint* ofsp   = counts + NODES_PAD;               // 200 KB

    const int NG = (N_NODES + 3) / 4;              // 12500
    const int GB = (N_NODES / 16 + 7) / 8;         // 391 blocks of 8 waves

    prep_kernel<<<16, 256, 0, stream>>>(W1, as1, ad1, W2, as2, ad2, WS1, WS2);
    bin_count_kernel<<<BBLK, 256, 0, stream>>>(dstv, counts);
    scan_kernel<<<1, 256, 0, stream>>>(counts, ofsp);
    bin_scatter_kernel<<<BBLK, 256, 0, stream>>>(srcv, dstv, ofsp, binned);
    build_kernel<<<NBUCK, 256, 0, stream>>>(binned, ofsp, degp, list);

    gemm_mfma_kernel<8, false><<<GB, 512, 0, stream>>>(x, W1, WS1, h1_16, asrc1, adst1, N_NODES);
    agg_kernel<8, true, true><<<NG, 256, 0, stream>>>(h1_16, list, degp, asrc1, adst1, b1, h1b);

    gemm_mfma_kernel<1, true><<<GB, 512, 0, stream>>>(h1b, W2, WS2, h2_16, asrc2, adst2, N_NODES);
    agg_kernel<1, false, false><<<NG, 256, 0, stream>>>(h2_16, list, degp, asrc2, adst2, b2, out);
}

// Round 5
// 125.510 us; speedup vs baseline: 2.7556x; 1.1609x over previous
//
#include <hip/hip_runtime.h>

#define N_NODES 50000
#define N_EDGES 800000
#define CAP 64
#define NBUCK 196          // ceil(50000/256)
#define NODES_PAD 50176    // NBUCK*256
#define BBLK 256           // edge blocks
#define EPB 3125           // edges per block
#define LOG2E 1.4426950408889634f

typedef unsigned int uint;
typedef unsigned short ushort;
typedef __attribute__((ext_vector_type(2))) float f32x2;
typedef __attribute__((ext_vector_type(4))) float f32x4;
typedef __attribute__((ext_vector_type(8))) short s16x8;

__device__ __forceinline__ f32x2 pk_add(f32x2 a, f32x2 b) {
    f32x2 d;
    asm("v_pk_add_f32 %0, %1, %2" : "=v"(d) : "v"(a), "v"(b));
    return d;
}
__device__ __forceinline__ f32x2 pk_mul(f32x2 a, f32x2 b) {
    f32x2 d;
    asm("v_pk_mul_f32 %0, %1, %2" : "=v"(d) : "v"(a), "v"(b));
    return d;
}
__device__ __forceinline__ f32x2 pk_fma(f32x2 a, f32x2 b, f32x2 c) {
    f32x2 d;
    asm("v_pk_fma_f32 %0, %1, %2, %3" : "=v"(d) : "v"(a), "v"(b), "v"(c));
    return d;
}

__device__ __forceinline__ ushort f2bf(float f) {   // RTNE f32 -> bf16
    uint u = __float_as_uint(f);
    u = (u + 0x7fffu + ((u >> 16) & 1u)) >> 16;
    return (ushort)u;
}
__device__ __forceinline__ float bf_lo(uint u) { return __uint_as_float(u << 16); }
__device__ __forceinline__ float bf_hi(uint u) { return __uint_as_float(u & 0xffff0000u); }

// ---------------- binned adjacency build ----------------
__global__ __launch_bounds__(256) void bin_count_kernel(
    const int* __restrict__ dstv, uint* __restrict__ counts)
{
    __shared__ uint hist[NBUCK];
    int tid = threadIdx.x, b = blockIdx.x;
    for (int k = tid; k < NBUCK; k += 256) hist[k] = 0;
    __syncthreads();
    int e0 = b * EPB;
    for (int i = tid; i < EPB; i += 256)
        atomicAdd(&hist[((uint)dstv[e0 + i]) >> 8], 1u);
    __syncthreads();
    for (int k = tid; k < NBUCK; k += 256) counts[k * BBLK + b] = hist[k];
}

// per-bucket local exclusive scan (196 blocks x 256) + bucket totals
__global__ __launch_bounds__(256) void scan1_kernel(
    const uint* __restrict__ counts, uint* __restrict__ ofs, uint* __restrict__ bsum)
{
    __shared__ uint wtot[4];
    int tid = threadIdx.x, k = blockIdx.x;
    int lane = tid & 63, wid = tid >> 6;
    uint v = counts[k * 256 + tid];
    uint inc = v;
    #pragma unroll
    for (int o = 1; o < 64; o <<= 1) {
        uint t = __shfl_up(inc, o);
        if (lane >= o) inc += t;
    }
    if (lane == 63) wtot[wid] = inc;
    __syncthreads();
    uint woff = 0;
    for (int w = 0; w < wid; w++) woff += wtot[w];
    uint excl = woff + inc - v;
    ofs[k * 256 + tid] = excl;
    if (tid == 255) bsum[k] = excl + v;
}

// top-level exclusive scan of bucket totals (1 block, 64 lanes, 4 per lane)
__global__ __launch_bounds__(64) void scan2_kernel(
    const uint* __restrict__ bsum, uint* __restrict__ bbase)
{
    int lane = threadIdx.x;
    int base = lane * 4;
    uint v[4];
    #pragma unroll
    for (int j = 0; j < 4; j++) v[j] = (base + j < NBUCK) ? bsum[base + j] : 0u;
    uint s = v[0] + v[1] + v[2] + v[3];
    uint inc = s;
    #pragma unroll
    for (int o = 1; o < 64; o <<= 1) {
        uint t = __shfl_up(inc, o);
        if (lane >= o) inc += t;
    }
    uint run = inc - s;
    #pragma unroll
    for (int j = 0; j < 4; j++) {
        if (base + j < NBUCK) { bbase[base + j] = run; run += v[j]; }
    }
}

__global__ __launch_bounds__(256) void bin_scatter_kernel(
    const int* __restrict__ srcv, const int* __restrict__ dstv,
    const uint* __restrict__ ofs, const uint* __restrict__ bbase,
    uint* __restrict__ binned)
{
    __shared__ uint cur[NBUCK];
    int tid = threadIdx.x, b = blockIdx.x;
    for (int k = tid; k < NBUCK; k += 256) cur[k] = ofs[k * BBLK + b] + bbase[k];
    __syncthreads();
    int e0 = b * EPB;
    for (int i = tid; i < EPB; i += 256) {
        int d = dstv[e0 + i], s = srcv[e0 + i];
        uint k = ((uint)d) >> 8;
        uint pos = atomicAdd(&cur[k], 1u);
        binned[pos] = (((uint)d & 255u) << 16) | (uint)s;
    }
}

// block per bucket: LDS-staged per-node ushort lists, dense coalesced writeback
__global__ __launch_bounds__(256) void build_kernel(
    const uint* __restrict__ binned, const uint* __restrict__ ofs,
    const uint* __restrict__ bbase,
    int* __restrict__ deg, ushort* __restrict__ list)
{
    __shared__ uint ldeg[256];
    __shared__ ushort llist[256 * CAP];     // 32 KB
    int tid = threadIdx.x, k = blockIdx.x;
    ldeg[tid] = 0;
    __syncthreads();
    uint start = ofs[k * 256] + bbase[k];
    uint end = (k == NBUCK - 1) ? N_EDGES : (ofs[(k + 1) * 256] + bbase[k + 1]);
    for (uint i = start + tid; i < end; i += 256) {
        uint p = binned[i];
        uint nl = (p >> 16) & 255u;
        uint slot = atomicAdd(&ldeg[nl], 1u);
        if (slot < CAP) llist[(nl << 6) + slot] = (ushort)(p & 0xFFFFu);
    }
    __syncthreads();
    int node0 = k << 8;
    deg[node0 + tid] = (int)ldeg[tid];
    uint4* d4 = (uint4*)(list + (size_t)node0 * CAP);
    const uint4* s4 = (const uint4*)llist;
    for (int i = tid; i < 256 * CAP * 2 / 16; i += 256) d4[i] = s4[i];
}

// ---------------- WS = (W @ S) * log2e  (attention dots folded into GEMM) ----------------
__global__ __launch_bounds__(256) void prep_kernel(
    const float* __restrict__ W1, const float* __restrict__ as1, const float* __restrict__ ad1,
    const float* __restrict__ W2, const float* __restrict__ as2, const float* __restrict__ ad2,
    float* __restrict__ WS1, float* __restrict__ WS2)
{
    int idx = blockIdx.x * 256 + threadIdx.x;
    if (idx < 2048) {
        int k = idx >> 4, j = idx & 15;
        const float* att = (j < 8) ? as1 : ad1;
        int head = j & 7;
        float s = 0.f;
        #pragma unroll
        for (int c = 0; c < 16; c++)
            s += W1[k * 128 + head * 16 + c] * att[head * 16 + c];
        WS1[idx] = s * LOG2E;
    } else if (idx < 4096) {
        int idx2 = idx - 2048;
        int k = idx2 >> 4, j = idx2 & 15;
        float s = 0.f;
        if (j < 2) {
            const float* att = j ? ad2 : as2;
            for (int c = 0; c < 128; c++) s += W2[k * 128 + c] * att[c];
        }
        WS2[idx2] = s * LOG2E;
    }
}

// ---------------- MFMA GEMM: h16 = bf16(A @ W), logits fused as 9th tile ----------------
template <int HEADS, bool ABF16>
__global__ __launch_bounds__(512) void gemm_mfma_kernel(
    const void* __restrict__ Av, const float* __restrict__ W,
    const float* __restrict__ WS,
    ushort* __restrict__ h16, float* __restrict__ a_src, float* __restrict__ a_dst,
    int nrows)
{
    __shared__ ushort Bf[2304 * 8];   // 36 KB
    int tid = threadIdx.x;
    for (int idx = tid; idx < 2304; idx += 512) {
        int t = idx >> 8;
        int rem = idx & 255;
        int kt = rem >> 6, L = rem & 63;
        int col = L & 15;
        int kb = ((L >> 4) << 3) + (kt << 5);
        ushort tmp[8];
        if (t < 8) {
            #pragma unroll
            for (int j = 0; j < 8; j++)
                tmp[j] = f2bf(W[(size_t)(kb + j) * 128 + (t << 4) + col]);
        } else {
            #pragma unroll
            for (int j = 0; j < 8; j++)
                tmp[j] = f2bf(WS[(kb + j) * 16 + col]);
        }
        uint p0 = (uint)tmp[0] | ((uint)tmp[1] << 16);
        uint p1 = (uint)tmp[2] | ((uint)tmp[3] << 16);
        uint p2 = (uint)tmp[4] | ((uint)tmp[5] << 16);
        uint p3 = (uint)tmp[6] | ((uint)tmp[7] << 16);
        *(uint4*)&Bf[idx * 8] = make_uint4(p0, p1, p2, p3);
    }
    __syncthreads();

    int lane = tid & 63;
    int wv = tid >> 6;
    int row0 = (blockIdx.x * 8 + wv) * 16;
    if (row0 >= nrows) return;

    int m = lane & 15, kg = lane >> 4;
    s16x8 afrag[4];
    if (ABF16) {
        const ushort* arow = (const ushort*)Av + (size_t)(row0 + m) * 128 + (kg << 3);
        #pragma unroll
        for (int kt = 0; kt < 4; kt++)
            afrag[kt] = *(const s16x8*)(arow + (kt << 5));
    } else {
        const float* arow = (const float*)Av + (size_t)(row0 + m) * 128 + (kg << 3);
        #pragma unroll
        for (int kt = 0; kt < 4; kt++) {
            float4 f0 = *(const float4*)(arow + (kt << 5));
            float4 f1 = *(const float4*)(arow + (kt << 5) + 4);
            union { s16x8 v; ushort us[8]; } uu;
            uu.us[0] = f2bf(f0.x); uu.us[1] = f2bf(f0.y);
            uu.us[2] = f2bf(f0.z); uu.us[3] = f2bf(f0.w);
            uu.us[4] = f2bf(f1.x); uu.us[5] = f2bf(f1.y);
            uu.us[6] = f2bf(f1.z); uu.us[7] = f2bf(f1.w);
            afrag[kt] = uu.v;
        }
    }

    f32x4 acc[9];
    #pragma unroll
    for (int t = 0; t < 9; t++) acc[t] = (f32x4){0.f, 0.f, 0.f, 0.f};
    #pragma unroll
    for (int t = 0; t < 9; t++) {
        #pragma unroll
        for (int kt = 0; kt < 4; kt++) {
            s16x8 b = *(const s16x8*)&Bf[(((t << 2) + kt) * 64 + lane) * 8];
            acc[t] = __builtin_amdgcn_mfma_f32_16x16x32_bf16(afrag[kt], b, acc[t], 0, 0, 0);
        }
    }

    // D layout: col = lane&15, row = (lane>>4)*4 + r   [m89]
    int colw = lane & 15;
    int rbase = row0 + ((lane >> 4) << 2);
    #pragma unroll
    for (int t = 0; t < 8; t++) {
        #pragma unroll
        for (int r = 0; r < 4; r++)
            h16[(size_t)(rbase + r) * 128 + (t << 4) + colw] = f2bf(acc[t][r]);
    }
    #pragma unroll
    for (int r = 0; r < 4; r++) {
        float v = acc[8][r];
        int row = rbase + r;
        if (HEADS == 8) {
            if (colw < 8) a_src[row * 8 + colw] = v;
            else          a_dst[row * 8 + (colw - 8)] = v;
        } else {
            if (colw == 0)      a_src[row] = v;
            else if (colw == 1) a_dst[row] = v;
        }
    }
}

// ---------------- edge softmax + aggregate. Wave/node; 32-lane-per-edge gather ----------------
// Logits pre-scaled by log2e (folded into WS): exp = exp2. Unnormalized aggregate, rcp at end.
template <int HEADS, bool ELU, bool OUT16>
__global__ __launch_bounds__(256) void agg_kernel(
    const ushort* __restrict__ h16, const ushort* __restrict__ list,
    const int* __restrict__ deg,
    const float* __restrict__ a_src, const float* __restrict__ a_dst,
    const float* __restrict__ bias, void* __restrict__ outv)
{
    __shared__ float w_lds[4][HEADS][65];
    __shared__ int s_lds[4][64];
    __shared__ float sh_l[4][8];
    int lane = threadIdx.x & 63;
    int wv = threadIdx.x >> 6;
    int n = blockIdx.x * 4 + wv;
    int d = min(deg[n], CAP);
    bool valid = lane < d;
    int s = valid ? (int)list[n * CAP + lane] : 0;
    s_lds[wv][lane] = s << 8;           // byte offset of bf16 row

    if (HEADS == 8) {
        float4 u0 = *(const float4*)&a_src[s * 8];
        float4 u1 = *(const float4*)&a_src[s * 8 + 4];
        float4 v0 = *(const float4*)&a_dst[n * 8];
        float4 v1 = *(const float4*)&a_dst[n * 8 + 4];
        float al[8] = {u0.x + v0.x, u0.y + v0.y, u0.z + v0.z, u0.w + v0.w,
                       u1.x + v1.x, u1.y + v1.y, u1.z + v1.z, u1.w + v1.w};
        float eh[8];
        #pragma unroll
        for (int hh = 0; hh < 8; hh++) {
            float a = fmaxf(al[hh], 0.2f * al[hh]);      // leaky_relu(0.2)
            eh[hh] = valid ? exp2f(a) : 0.f;
            w_lds[wv][hh][lane] = eh[hh];
        }
        f32x2 s01 = {eh[0], eh[1]}, s23 = {eh[2], eh[3]};
        f32x2 s45 = {eh[4], eh[5]}, s67 = {eh[6], eh[7]};
        auto lvl = [&](int mm) {
            f32x2 t;
            t.x = __shfl_xor(s01.x, mm); t.y = __shfl_xor(s01.y, mm); s01 = pk_add(s01, t);
            t.x = __shfl_xor(s23.x, mm); t.y = __shfl_xor(s23.y, mm); s23 = pk_add(s23, t);
            t.x = __shfl_xor(s45.x, mm); t.y = __shfl_xor(s45.y, mm); s45 = pk_add(s45, t);
            t.x = __shfl_xor(s67.x, mm); t.y = __shfl_xor(s67.y, mm); s67 = pk_add(s67, t);
        };
        lvl(1); lvl(2); lvl(4); lvl(8);
        if (d > 16) lvl(16);
        if (d > 32) lvl(32);
        if (lane == 0) {
            *(f32x2*)&sh_l[wv][0] = s01; *(f32x2*)&sh_l[wv][2] = s23;
            *(f32x2*)&sh_l[wv][4] = s45; *(f32x2*)&sh_l[wv][6] = s67;
        }
    } else {
        float a = a_src[s] + a_dst[n];
        a = fmaxf(a, 0.2f * a);
        float eh0 = valid ? exp2f(a) : 0.f;
        w_lds[wv][0][lane] = eh0;
        float sh = eh0;
        sh += __shfl_xor(sh, 1); sh += __shfl_xor(sh, 2);
        sh += __shfl_xor(sh, 4); sh += __shfl_xor(sh, 8);
        if (d > 16) sh += __shfl_xor(sh, 16);
        if (d > 32) sh += __shfl_xor(sh, 32);
        if (lane == 0) sh_l[wv][0] = sh;
    }
    // no __syncthreads needed: all LDS traffic is wave-private

    // gather: 32 lanes per edge, 4 channels per lane, 2 edges per round, chunk=8
    int half = lane >> 5;
    int lq = lane & 31;
    int c0 = lq << 2;
    int g = (HEADS == 8) ? (lq >> 2) : 0;
    const char* hp = (const char*)h16 + (c0 << 1);
    f32x2 acc01 = {0.f, 0.f}, acc23 = {0.f, 0.f};
    int d8 = (d + 7) & ~7;
    for (int e0 = 0; e0 < d8; e0 += 8) {
        int soff[4]; float wv4[4]; uint2 u[4];
        #pragma unroll
        for (int r = 0; r < 4; r++) {
            int e = e0 + (r << 1) + half;
            soff[r] = s_lds[wv][e];
            wv4[r] = w_lds[wv][g][e];
        }
        #pragma unroll
        for (int r = 0; r < 4; r++)
            u[r] = *(const uint2*)(hp + soff[r]);
        #pragma unroll
        for (int r = 0; r < 4; r++) {
            f32x2 wp = {wv4[r], wv4[r]};
            f32x2 lo = {bf_lo(u[r].x), bf_hi(u[r].x)};
            f32x2 hi = {bf_lo(u[r].y), bf_hi(u[r].y)};
            acc01 = pk_fma(wp, lo, acc01);
            acc23 = pk_fma(wp, hi, acc23);
        }
    }
    // combine the two edge-halves
    f32x2 t;
    t.x = __shfl_xor(acc01.x, 32); t.y = __shfl_xor(acc01.y, 32); acc01 = pk_add(acc01, t);
    t.x = __shfl_xor(acc23.x, 32); t.y = __shfl_xor(acc23.y, 32); acc23 = pk_add(acc23, t);

    // normalize + bias (+ ELU) + store (lanes 0..31 cover all 128 channels)
    float shv = sh_l[wv][g];
    float r = __builtin_amdgcn_rcpf(shv + 1e-16f);
    f32x2 rr = {r, r};
    acc01 = pk_mul(acc01, rr);
    acc23 = pk_mul(acc23, rr);
    float4 bv = *(const float4*)&bias[c0];
    float o0 = acc01.x + bv.x, o1 = acc01.y + bv.y;
    float o2 = acc23.x + bv.z, o3 = acc23.y + bv.w;
    if (ELU) {
        o0 = o0 > 0.f ? o0 : __expf(o0) - 1.f;
        o1 = o1 > 0.f ? o1 : __expf(o1) - 1.f;
        o2 = o2 > 0.f ? o2 : __expf(o2) - 1.f;
        o3 = o3 > 0.f ? o3 : __expf(o3) - 1.f;
    }
    if (lane < 32) {
        if (OUT16) {
            uint2 pk;
            pk.x = (uint)f2bf(o0) | ((uint)f2bf(o1) << 16);
            pk.y = (uint)f2bf(o2) | ((uint)f2bf(o3) << 16);
            *(uint2*)((ushort*)outv + (size_t)n * 128 + c0) = pk;
        } else {
            *(float4*)((float*)outv + (size_t)n * 128 + c0) = make_float4(o0, o1, o2, o3);
        }
    }
}

extern "C" void kernel_launch(void* const* d_in, const int* in_sizes, int n_in,
                              void* d_out, int out_size, void* d_ws, size_t ws_size,
                              hipStream_t stream)
{
    (void)in_sizes; (void)n_in; (void)out_size; (void)ws_size;
    const float* x   = (const float*)d_in[0];
    const int*   ei  = (const int*)d_in[1];
    const float* W1  = (const float*)d_in[2];
    const float* as1 = (const float*)d_in[3];
    const float* ad1 = (const float*)d_in[4];
    const float* b1  = (const float*)d_in[5];
    const float* W2  = (const float*)d_in[6];
    const float* as2 = (const float*)d_in[7];
    const float* ad2 = (const float*)d_in[8];
    const float* b2  = (const float*)d_in[9];
    float* out = (float*)d_out;
    const int* srcv = ei;
    const int* dstv = ei + N_EDGES;

    char* ws = (char*)d_ws;
    size_t off = 0;
    auto alloc = [&](size_t bytes) {
        void* p = ws + off;
        off += (bytes + 255) & ~(size_t)255;
        return p;
    };
    ushort* h1_16 = (ushort*)alloc((size_t)N_NODES * 128 * 2);
    ushort* h2_16 = (ushort*)alloc((size_t)N_NODES * 128 * 2);
    ushort* h1b   = (ushort*)alloc((size_t)N_NODES * 128 * 2);   // bf16 inter-layer act
    float*  asrc1 = (float*)alloc((size_t)N_NODES * 8 * 4);
    float*  adst1 = (float*)alloc((size_t)N_NODES * 8 * 4);
    float*  asrc2 = (float*)alloc((size_t)N_NODES * 4);
    float*  adst2 = (float*)alloc((size_t)N_NODES * 4);
    int*    degp  = (int*)alloc((size_t)NODES_PAD * 4);
    ushort* list  = (ushort*)alloc((size_t)NODES_PAD * CAP * 2);
    float*  WS1   = (float*)alloc(128 * 16 * 4);
    float*  WS2   = (float*)alloc(128 * 16 * 4);
    // bin scratch aliases into h1b (fully consumed before agg1 writes h1b)
    uint* binned = (uint*)h1b;                       // 3.2 MB
    uint* counts = binned + N_EDGES;                 // 200 KB
    uint* ofsp   = counts + NODES_PAD;               // 200 KB
    uint* bsum   = ofsp + NODES_PAD;                 // 784 B
    uint* bbase  = bsum + NBUCK;                     // 784 B

    const int NG = (N_NODES + 3) / 4;              // 12500
    const int GB = (N_NODES / 16 + 7) / 8;         // 391 blocks of 8 waves

    prep_kernel<<<16, 256, 0, stream>>>(W1, as1, ad1, W2, as2, ad2, WS1, WS2);
    bin_count_kernel<<<BBLK, 256, 0, stream>>>(dstv, counts);
    scan1_kernel<<<NBUCK, 256, 0, stream>>>(counts, ofsp, bsum);
    scan2_kernel<<<1, 64, 0, stream>>>(bsum, bbase);
    bin_scatter_kernel<<<BBLK, 256, 0, stream>>>(srcv, dstv, ofsp, bbase, binned);
    build_kernel<<<NBUCK, 256, 0, stream>>>(binned, ofsp, bbase, degp, list);

    gemm_mfma_kernel<8, false><<<GB, 512, 0, stream>>>(x, W1, WS1, h1_16, asrc1, adst1, N_NODES);
    agg_kernel<8, true, true><<<NG, 256, 0, stream>>>(h1_16, list, degp, asrc1, adst1, b1, h1b);

    gemm_mfma_kernel<1, true><<<GB, 512, 0, stream>>>(h1b, W2, WS2, h2_16, asrc2, adst2, N_NODES);
    agg_kernel<1, false, false><<<NG, 256, 0, stream>>>(h2_16, list, degp, asrc2, adst2, b2, out);
}

// Round 6
// 124.656 us; speedup vs baseline: 2.7744x; 1.0069x over previous
//
#include <hip/hip_runtime.h>

#define N_NODES 50000
#define N_EDGES 800000
#define CAP 64
#define NBUCK 196          // ceil(50000/256)
#define NODES_PAD 50176    // NBUCK*256
#define BBLK 256           // edge blocks
#define EPB 3125           // edges per block
#define LOG2E 1.4426950408889634f

typedef unsigned int uint;
typedef unsigned short ushort;
typedef __attribute__((ext_vector_type(2))) float f32x2;
typedef __attribute__((ext_vector_type(4))) float f32x4;
typedef __attribute__((ext_vector_type(8))) short s16x8;

__device__ __forceinline__ f32x2 pk_add(f32x2 a, f32x2 b) {
    f32x2 d;
    asm("v_pk_add_f32 %0, %1, %2" : "=v"(d) : "v"(a), "v"(b));
    return d;
}
__device__ __forceinline__ f32x2 pk_mul(f32x2 a, f32x2 b) {
    f32x2 d;
    asm("v_pk_mul_f32 %0, %1, %2" : "=v"(d) : "v"(a), "v"(b));
    return d;
}
__device__ __forceinline__ f32x2 pk_fma(f32x2 a, f32x2 b, f32x2 c) {
    f32x2 d;
    asm("v_pk_fma_f32 %0, %1, %2, %3" : "=v"(d) : "v"(a), "v"(b), "v"(c));
    return d;
}

__device__ __forceinline__ ushort f2bf(float f) {   // RTNE f32 -> bf16
    uint u = __float_as_uint(f);
    u = (u + 0x7fffu + ((u >> 16) & 1u)) >> 16;
    return (ushort)u;
}
__device__ __forceinline__ float bf_lo(uint u) { return __uint_as_float(u << 16); }
__device__ __forceinline__ float bf_hi(uint u) { return __uint_as_float(u & 0xffff0000u); }

// ---------------- binned adjacency build ----------------
__global__ __launch_bounds__(256) void bin_count_kernel(
    const int* __restrict__ dstv, uint* __restrict__ counts)
{
    __shared__ uint hist[NBUCK];
    int tid = threadIdx.x, b = blockIdx.x;
    for (int k = tid; k < NBUCK; k += 256) hist[k] = 0;
    __syncthreads();
    int e0 = b * EPB;
    for (int i = tid; i < EPB; i += 256)
        atomicAdd(&hist[((uint)dstv[e0 + i]) >> 8], 1u);
    __syncthreads();
    for (int k = tid; k < NBUCK; k += 256) counts[k * BBLK + b] = hist[k];
}

// per-bucket local exclusive scan (196 blocks x 256) + bucket totals
__global__ __launch_bounds__(256) void scan1_kernel(
    const uint* __restrict__ counts, uint* __restrict__ ofs, uint* __restrict__ bsum)
{
    __shared__ uint wtot[4];
    int tid = threadIdx.x, k = blockIdx.x;
    int lane = tid & 63, wid = tid >> 6;
    uint v = counts[k * 256 + tid];
    uint inc = v;
    #pragma unroll
    for (int o = 1; o < 64; o <<= 1) {
        uint t = __shfl_up(inc, o);
        if (lane >= o) inc += t;
    }
    if (lane == 63) wtot[wid] = inc;
    __syncthreads();
    uint woff = 0;
    for (int w = 0; w < wid; w++) woff += wtot[w];
    uint excl = woff + inc - v;
    ofs[k * 256 + tid] = excl;
    if (tid == 255) bsum[k] = excl + v;
}

// top-level exclusive scan of bucket totals
__global__ __launch_bounds__(64) void scan2_kernel(
    const uint* __restrict__ bsum, uint* __restrict__ bbase)
{
    int lane = threadIdx.x;
    int base = lane * 4;
    uint v[4];
    #pragma unroll
    for (int j = 0; j < 4; j++) v[j] = (base + j < NBUCK) ? bsum[base + j] : 0u;
    uint s = v[0] + v[1] + v[2] + v[3];
    uint inc = s;
    #pragma unroll
    for (int o = 1; o < 64; o <<= 1) {
        uint t = __shfl_up(inc, o);
        if (lane >= o) inc += t;
    }
    uint run = inc - s;
    #pragma unroll
    for (int j = 0; j < 4; j++) {
        if (base + j < NBUCK) { bbase[base + j] = run; run += v[j]; }
    }
}

__global__ __launch_bounds__(256) void bin_scatter_kernel(
    const int* __restrict__ srcv, const int* __restrict__ dstv,
    const uint* __restrict__ ofs, const uint* __restrict__ bbase,
    uint* __restrict__ binned)
{
    __shared__ uint cur[NBUCK];
    int tid = threadIdx.x, b = blockIdx.x;
    for (int k = tid; k < NBUCK; k += 256) cur[k] = ofs[k * BBLK + b] + bbase[k];
    __syncthreads();
    int e0 = b * EPB;
    for (int i = tid; i < EPB; i += 256) {
        int d = dstv[e0 + i], s = srcv[e0 + i];
        uint k = ((uint)d) >> 8;
        uint pos = atomicAdd(&cur[k], 1u);
        binned[pos] = (((uint)d & 255u) << 16) | (uint)s;
    }
}

// block per bucket: LDS-staged per-node ushort lists, dense coalesced writeback
__global__ __launch_bounds__(256) void build_kernel(
    const uint* __restrict__ binned, const uint* __restrict__ ofs,
    const uint* __restrict__ bbase,
    int* __restrict__ deg, ushort* __restrict__ list)
{
    __shared__ uint ldeg[256];
    __shared__ ushort llist[256 * CAP];     // 32 KB
    int tid = threadIdx.x, k = blockIdx.x;
    ldeg[tid] = 0;
    __syncthreads();
    uint start = ofs[k * 256] + bbase[k];
    uint end = (k == NBUCK - 1) ? N_EDGES : (ofs[(k + 1) * 256] + bbase[k + 1]);
    for (uint i = start + tid; i < end; i += 256) {
        uint p = binned[i];
        uint nl = (p >> 16) & 255u;
        uint slot = atomicAdd(&ldeg[nl], 1u);
        if (slot < CAP) llist[(nl << 6) + slot] = (ushort)(p & 0xFFFFu);
    }
    __syncthreads();
    int node0 = k << 8;
    deg[node0 + tid] = (int)ldeg[tid];
    uint4* d4 = (uint4*)(list + (size_t)node0 * CAP);
    const uint4* s4 = (const uint4*)llist;
    for (int i = tid; i < 256 * CAP * 2 / 16; i += 256) d4[i] = s4[i];
}

// ---------------- WS = (W @ S) * log2e ----------------
__global__ __launch_bounds__(256) void prep_kernel(
    const float* __restrict__ W1, const float* __restrict__ as1, const float* __restrict__ ad1,
    const float* __restrict__ W2, const float* __restrict__ as2, const float* __restrict__ ad2,
    float* __restrict__ WS1, float* __restrict__ WS2)
{
    int idx = blockIdx.x * 256 + threadIdx.x;
    if (idx < 2048) {
        int k = idx >> 4, j = idx & 15;
        const float* att = (j < 8) ? as1 : ad1;
        int head = j & 7;
        float s = 0.f;
        #pragma unroll
        for (int c = 0; c < 16; c++)
            s += W1[k * 128 + head * 16 + c] * att[head * 16 + c];
        WS1[idx] = s * LOG2E;
    } else if (idx < 4096) {
        int idx2 = idx - 2048;
        int k = idx2 >> 4, j = idx2 & 15;
        float s = 0.f;
        if (j < 2) {
            const float* att = j ? ad2 : as2;
            for (int c = 0; c < 128; c++) s += W2[k * 128 + c] * att[c];
        }
        WS2[idx2] = s * LOG2E;
    }
}

// ---------------- MFMA GEMM: h16 = bf16(A @ W), logits fused as 9th tile ----------------
template <int HEADS, bool ABF16>
__global__ __launch_bounds__(512) void gemm_mfma_kernel(
    const void* __restrict__ Av, const float* __restrict__ W,
    const float* __restrict__ WS,
    ushort* __restrict__ h16, float* __restrict__ a_src, float* __restrict__ a_dst,
    int nrows)
{
    __shared__ ushort Bf[2304 * 8];   // 36 KB
    int tid = threadIdx.x;
    for (int idx = tid; idx < 2304; idx += 512) {
        int t = idx >> 8;
        int rem = idx & 255;
        int kt = rem >> 6, L = rem & 63;
        int col = L & 15;
        int kb = ((L >> 4) << 3) + (kt << 5);
        ushort tmp[8];
        if (t < 8) {
            #pragma unroll
            for (int j = 0; j < 8; j++)
                tmp[j] = f2bf(W[(size_t)(kb + j) * 128 + (t << 4) + col]);
        } else {
            #pragma unroll
            for (int j = 0; j < 8; j++)
                tmp[j] = f2bf(WS[(kb + j) * 16 + col]);
        }
        uint p0 = (uint)tmp[0] | ((uint)tmp[1] << 16);
        uint p1 = (uint)tmp[2] | ((uint)tmp[3] << 16);
        uint p2 = (uint)tmp[4] | ((uint)tmp[5] << 16);
        uint p3 = (uint)tmp[6] | ((uint)tmp[7] << 16);
        *(uint4*)&Bf[idx * 8] = make_uint4(p0, p1, p2, p3);
    }
    __syncthreads();

    int lane = tid & 63;
    int wv = tid >> 6;
    int row0 = (blockIdx.x * 8 + wv) * 16;
    if (row0 >= nrows) return;

    int m = lane & 15, kg = lane >> 4;
    s16x8 afrag[4];
    if (ABF16) {
        const ushort* arow = (const ushort*)Av + (size_t)(row0 + m) * 128 + (kg << 3);
        #pragma unroll
        for (int kt = 0; kt < 4; kt++)
            afrag[kt] = *(const s16x8*)(arow + (kt << 5));
    } else {
        const float* arow = (const float*)Av + (size_t)(row0 + m) * 128 + (kg << 3);
        #pragma unroll
        for (int kt = 0; kt < 4; kt++) {
            float4 f0 = *(const float4*)(arow + (kt << 5));
            float4 f1 = *(const float4*)(arow + (kt << 5) + 4);
            union { s16x8 v; ushort us[8]; } uu;
            uu.us[0] = f2bf(f0.x); uu.us[1] = f2bf(f0.y);
            uu.us[2] = f2bf(f0.z); uu.us[3] = f2bf(f0.w);
            uu.us[4] = f2bf(f1.x); uu.us[5] = f2bf(f1.y);
            uu.us[6] = f2bf(f1.z); uu.us[7] = f2bf(f1.w);
            afrag[kt] = uu.v;
        }
    }

    f32x4 acc[9];
    #pragma unroll
    for (int t = 0; t < 9; t++) acc[t] = (f32x4){0.f, 0.f, 0.f, 0.f};
    #pragma unroll
    for (int t = 0; t < 9; t++) {
        #pragma unroll
        for (int kt = 0; kt < 4; kt++) {
            s16x8 b = *(const s16x8*)&Bf[(((t << 2) + kt) * 64 + lane) * 8];
            acc[t] = __builtin_amdgcn_mfma_f32_16x16x32_bf16(afrag[kt], b, acc[t], 0, 0, 0);
        }
    }

    // D layout: col = lane&15, row = (lane>>4)*4 + r   [m89]
    int colw = lane & 15;
    int rbase = row0 + ((lane >> 4) << 2);
    #pragma unroll
    for (int t = 0; t < 8; t++) {
        #pragma unroll
        for (int r = 0; r < 4; r++)
            h16[(size_t)(rbase + r) * 128 + (t << 4) + colw] = f2bf(acc[t][r]);
    }
    #pragma unroll
    for (int r = 0; r < 4; r++) {
        float v = acc[8][r];
        int row = rbase + r;
        if (HEADS == 8) {
            if (colw < 8) a_src[row * 8 + colw] = v;
            else          a_dst[row * 8 + (colw - 8)] = v;
        } else {
            if (colw == 0)      a_src[row] = v;
            else if (colw == 1) a_dst[row] = v;
        }
    }
}

// ---------------- edge softmax + aggregate. Wave/node; pipelined 16-edge chunks ----------------
// Logits pre-scaled by log2e: exp = exp2. Unnormalized aggregate, rcp at end.
template <int HEADS, bool ELU, bool OUT16>
__global__ __launch_bounds__(256) void agg_kernel(
    const ushort* __restrict__ h16, const ushort* __restrict__ list,
    const int* __restrict__ deg,
    const float* __restrict__ a_src, const float* __restrict__ a_dst,
    const float* __restrict__ bias, void* __restrict__ outv)
{
    __shared__ float w_lds[4][HEADS][65];
    __shared__ int s_lds[4][64];
    __shared__ float sh_l[4][8];
    int lane = threadIdx.x & 63;
    int wv = threadIdx.x >> 6;
    int n = blockIdx.x * 4 + wv;
    int d = min(deg[n], CAP);
    bool valid = lane < d;
    int s = valid ? (int)list[n * CAP + lane] : 0;
    s_lds[wv][lane] = s << 8;           // byte offset of bf16 row

    // ---- issue logit gathers first (softmax needs them soonest) ----
    float4 u0, u1, v0, v1;              // HEADS==8
    float a1s = 0.f, a1d = 0.f;         // HEADS==1
    if (HEADS == 8) {
        u0 = *(const float4*)&a_src[s * 8];
        u1 = *(const float4*)&a_src[s * 8 + 4];
        v0 = *(const float4*)&a_dst[n * 8];
        v1 = *(const float4*)&a_dst[n * 8 + 4];
    } else {
        a1s = a_src[s]; a1d = a_dst[n];
    }

    // ---- pre-issue first 16-edge chunk of h-row gathers (hide under softmax) ----
    int half = lane >> 5;
    int lq = lane & 31;
    int c0 = lq << 2;
    int g = (HEADS == 8) ? (lq >> 2) : 0;
    const char* hp = (const char*)h16 + (c0 << 1);
    int d16 = (d + 15) & ~15;

    uint2 uA[8], uB[8];
    auto issue = [&](uint2 (&u)[8], int base) {
        #pragma unroll
        for (int r = 0; r < 8; r++) {
            int e = base + (r << 1) + half;
            u[r] = *(const uint2*)(hp + s_lds[wv][e]);
        }
    };
    f32x2 acc01 = {0.f, 0.f}, acc23 = {0.f, 0.f};
    auto fmachunk = [&](uint2 (&u)[8], int base) {
        #pragma unroll
        for (int r = 0; r < 8; r++) {
            int e = base + (r << 1) + half;
            float w = w_lds[wv][g][e];
            f32x2 wp = {w, w};
            f32x2 lo = {bf_lo(u[r].x), bf_hi(u[r].x)};
            f32x2 hi = {bf_lo(u[r].y), bf_hi(u[r].y)};
            acc01 = pk_fma(wp, lo, acc01);
            acc23 = pk_fma(wp, hi, acc23);
        }
    };

    if (d16 > 0) issue(uA, 0);

    // ---- softmax (runs while chunk-0 loads are in flight) ----
    if (HEADS == 8) {
        float al[8] = {u0.x + v0.x, u0.y + v0.y, u0.z + v0.z, u0.w + v0.w,
                       u1.x + v1.x, u1.y + v1.y, u1.z + v1.z, u1.w + v1.w};
        float eh[8];
        #pragma unroll
        for (int hh = 0; hh < 8; hh++) {
            float a = fmaxf(al[hh], 0.2f * al[hh]);      // leaky_relu(0.2)
            eh[hh] = valid ? exp2f(a) : 0.f;
            w_lds[wv][hh][lane] = eh[hh];
        }
        f32x2 s01 = {eh[0], eh[1]}, s23 = {eh[2], eh[3]};
        f32x2 s45 = {eh[4], eh[5]}, s67 = {eh[6], eh[7]};
        auto lvl = [&](int mm) {
            f32x2 t;
            t.x = __shfl_xor(s01.x, mm); t.y = __shfl_xor(s01.y, mm); s01 = pk_add(s01, t);
            t.x = __shfl_xor(s23.x, mm); t.y = __shfl_xor(s23.y, mm); s23 = pk_add(s23, t);
            t.x = __shfl_xor(s45.x, mm); t.y = __shfl_xor(s45.y, mm); s45 = pk_add(s45, t);
            t.x = __shfl_xor(s67.x, mm); t.y = __shfl_xor(s67.y, mm); s67 = pk_add(s67, t);
        };
        lvl(1); lvl(2); lvl(4); lvl(8);
        if (d > 16) lvl(16);
        if (d > 32) lvl(32);
        if (lane == 0) {
            *(f32x2*)&sh_l[wv][0] = s01; *(f32x2*)&sh_l[wv][2] = s23;
            *(f32x2*)&sh_l[wv][4] = s45; *(f32x2*)&sh_l[wv][6] = s67;
        }
    } else {
        float a = a1s + a1d;
        a = fmaxf(a, 0.2f * a);
        float eh0 = valid ? exp2f(a) : 0.f;
        w_lds[wv][0][lane] = eh0;
        float sh = eh0;
        sh += __shfl_xor(sh, 1); sh += __shfl_xor(sh, 2);
        sh += __shfl_xor(sh, 4); sh += __shfl_xor(sh, 8);
        if (d > 16) sh += __shfl_xor(sh, 16);
        if (d > 32) sh += __shfl_xor(sh, 32);
        if (lane == 0) sh_l[wv][0] = sh;
    }
    // all LDS traffic is wave-private: no __syncthreads needed

    // ---- pipelined gather: ping-pong 16-edge chunks, wave-uniform branches ----
    if (d16 > 16) issue(uB, 16);
    if (d16 > 0)  fmachunk(uA, 0);
    if (d16 > 32) issue(uA, 32);
    if (d16 > 16) fmachunk(uB, 16);
    if (d16 > 48) issue(uB, 48);
    if (d16 > 32) fmachunk(uA, 32);
    if (d16 > 48) fmachunk(uB, 48);

    // combine the two edge-halves
    f32x2 t;
    t.x = __shfl_xor(acc01.x, 32); t.y = __shfl_xor(acc01.y, 32); acc01 = pk_add(acc01, t);
    t.x = __shfl_xor(acc23.x, 32); t.y = __shfl_xor(acc23.y, 32); acc23 = pk_add(acc23, t);

    // normalize + bias (+ ELU) + store (lanes 0..31 cover all 128 channels)
    float shv = sh_l[wv][g];
    float r = __builtin_amdgcn_rcpf(shv + 1e-16f);
    f32x2 rr = {r, r};
    acc01 = pk_mul(acc01, rr);
    acc23 = pk_mul(acc23, rr);
    float4 bv = *(const float4*)&bias[c0];
    float o0 = acc01.x + bv.x, o1 = acc01.y + bv.y;
    float o2 = acc23.x + bv.z, o3 = acc23.y + bv.w;
    if (ELU) {
        o0 = o0 > 0.f ? o0 : __expf(o0) - 1.f;
        o1 = o1 > 0.f ? o1 : __expf(o1) - 1.f;
        o2 = o2 > 0.f ? o2 : __expf(o2) - 1.f;
        o3 = o3 > 0.f ? o3 : __expf(o3) - 1.f;
    }
    if (lane < 32) {
        if (OUT16) {
            uint2 pk;
            pk.x = (uint)f2bf(o0) | ((uint)f2bf(o1) << 16);
            pk.y = (uint)f2bf(o2) | ((uint)f2bf(o3) << 16);
            *(uint2*)((ushort*)outv + (size_t)n * 128 + c0) = pk;
        } else {
            *(float4*)((float*)outv + (size_t)n * 128 + c0) = make_float4(o0, o1, o2, o3);
        }
    }
}

extern "C" void kernel_launch(void* const* d_in, const int* in_sizes, int n_in,
                              void* d_out, int out_size, void* d_ws, size_t ws_size,
                              hipStream_t stream)
{
    (void)in_sizes; (void)n_in; (void)out_size; (void)ws_size;
    const float* x   = (const float*)d_in[0];
    const int*   ei  = (const int*)d_in[1];
    const float* W1  = (const float*)d_in[2];
    const float* as1 = (const float*)d_in[3];
    const float* ad1 = (const float*)d_in[4];
    const float* b1  = (const float*)d_in[5];
    const float* W2  = (const float*)d_in[6];
    const float* as2 = (const float*)d_in[7];
    const float* ad2 = (const float*)d_in[8];
    const float* b2  = (const float*)d_in[9];
    float* out = (float*)d_out;
    const int* srcv = ei;
    const int* dstv = ei + N_EDGES;

    char* ws = (char*)d_ws;
    size_t off = 0;
    auto alloc = [&](size_t bytes) {
        void* p = ws + off;
        off += (bytes + 255) & ~(size_t)255;
        return p;
    };
    ushort* h1_16 = (ushort*)alloc((size_t)N_NODES * 128 * 2);
    ushort* h2_16 = (ushort*)alloc((size_t)N_NODES * 128 * 2);
    ushort* h1b   = (ushort*)alloc((size_t)N_NODES * 128 * 2);   // bf16 inter-layer act
    float*  asrc1 = (float*)alloc((size_t)N_NODES * 8 * 4);
    float*  adst1 = (float*)alloc((size_t)N_NODES * 8 * 4);
    float*  asrc2 = (float*)alloc((size_t)N_NODES * 4);
    float*  adst2 = (float*)alloc((size_t)N_NODES * 4);
    int*    degp  = (int*)alloc((size_t)NODES_PAD * 4);
    ushort* list  = (ushort*)alloc((size_t)NODES_PAD * CAP * 2);
    float*  WS1   = (float*)alloc(128 * 16 * 4);
    float*  WS2   = (float*)alloc(128 * 16 * 4);
    // bin scratch aliases into h1b (fully consumed before agg1 writes h1b)
    uint* binned = (uint*)h1b;                       // 3.2 MB
    uint* counts = binned + N_EDGES;                 // 200 KB
    uint* ofsp   = counts + NODES_PAD;               // 200 KB
    uint* bsum   = ofsp + NODES_PAD;                 // 784 B
    uint* bbase  = bsum + NBUCK;                     // 784 B

    const int NG = (N_NODES + 3) / 4;              // 12500
    const int GB = (N_NODES / 16 + 7) / 8;         // 391 blocks of 8 waves

    prep_kernel<<<16, 256, 0, stream>>>(W1, as1, ad1, W2, as2, ad2, WS1, WS2);
    bin_count_kernel<<<BBLK, 256, 0, stream>>>(dstv, counts);
    scan1_kernel<<<NBUCK, 256, 0, stream>>>(counts, ofsp, bsum);
    scan2_kernel<<<1, 64, 0, stream>>>(bsum, bbase);
    bin_scatter_kernel<<<BBLK, 256, 0, stream>>>(srcv, dstv, ofsp, bbase, binned);
    build_kernel<<<NBUCK, 256, 0, stream>>>(binned, ofsp, bbase, degp, list);

    gemm_mfma_kernel<8, false><<<GB, 512, 0, stream>>>(x, W1, WS1, h1_16, asrc1, adst1, N_NODES);
    agg_kernel<8, true, true><<<NG, 256, 0, stream>>>(h1_16, list, degp, asrc1, adst1, b1, h1b);

    gemm_mfma_kernel<1, true><<<GB, 512, 0, stream>>>(h1b, W2, WS2, h2_16, asrc2, adst2, N_NODES);
    agg_kernel<1, false, false><<<NG, 256, 0, stream>>>(h2_16, list, degp, asrc2, adst2, b2, out);
}